// Round 2
// baseline (1325.817 us; speedup 1.0000x reference)
//
#include <hip/hip_runtime.h>

static inline size_t align_up(size_t x, size_t a) { return (x + a - 1) & ~(a - 1); }

// ---------------- CSR build ----------------
// edge_index is int32 on device (harness converts integer inputs to int32):
// ei[0..E) = src, ei[E..2E) = dst

__global__ void hist_kernel(const int* __restrict__ ei, int* __restrict__ deg, int E) {
  int e = blockIdx.x * 256 + threadIdx.x;
  if (e < E) atomicAdd(&deg[ei[(size_t)E + e]], 1);
}

__global__ void scan_blocks_kernel(const int* __restrict__ deg, int* __restrict__ row_ptr,
                                   int* __restrict__ blk, int n) {
  __shared__ int sb[1024];
  int t = threadIdx.x;
  int i = blockIdx.x * 1024 + t;
  int v = (i < n) ? deg[i] : 0;
  sb[t] = v;
  __syncthreads();
  int acc = v;
  for (int d = 1; d < 1024; d <<= 1) {
    int add = (t >= d) ? sb[t - d] : 0;
    __syncthreads();
    acc += add;
    sb[t] = acc;
    __syncthreads();
  }
  if (i < n) row_ptr[i + 1] = acc;
  if (t == 1023) blk[blockIdx.x] = acc;
  if (i == 0) row_ptr[0] = 0;
}

__global__ void scan_top_kernel(int* blk, int nb) {
  if (threadIdx.x == 0 && blockIdx.x == 0) {
    int s = 0;
    for (int b = 0; b < nb; ++b) { int v = blk[b]; blk[b] = s; s += v; }
  }
}

__global__ void scan_add_kernel(int* __restrict__ row_ptr, const int* __restrict__ blk, int n) {
  int i = blockIdx.x * 1024 + threadIdx.x;
  if (i < n) row_ptr[i + 1] += blk[i >> 10];
}

__global__ void cursor_kernel(const int* __restrict__ row_ptr, int* __restrict__ cursor, int n) {
  int i = blockIdx.x * 256 + threadIdx.x;
  if (i < n) cursor[i] = row_ptr[i];
}

__global__ void scatter_kernel(const int* __restrict__ ei, int* __restrict__ cursor,
                               int* __restrict__ col, int E) {
  int e = blockIdx.x * 256 + threadIdx.x;
  if (e < E) {
    int d = ei[(size_t)E + e];
    int slot = atomicAdd(&cursor[d], 1);
    col[slot] = ei[e];
  }
}

// ---------------- mean aggregation: M[n] = mean over in-neighbors of xin ----------------
// one wave per node; lane handles 2 dims (float2)

__global__ void aggr_kernel(const float* __restrict__ xin, const int* __restrict__ row_ptr,
                            const int* __restrict__ col, float* __restrict__ M, int n) {
  int node = blockIdx.x * 4 + (threadIdx.x >> 6);
  if (node >= n) return;
  int lane = threadIdx.x & 63;
  int beg = row_ptr[node], end = row_ptr[node + 1];
  float sx = 0.f, sy = 0.f;
  for (int e = beg; e < end; ++e) {
    int c = col[e];
    float2 v = *(const float2*)(xin + (size_t)c * 128 + lane * 2);
    sx += v.x;
    sy += v.y;
  }
  int d = end - beg;
  float inv = 1.0f / (float)(d > 1 ? d : 1);
  float2 o;
  o.x = sx * inv;
  o.y = sy * inv;
  *(float2*)(M + (size_t)node * 128 + lane * 2) = o;
}

// ---------------- fused SAGE linear: H = relu(M @ Wl^T + b + X @ Wr^T) ----------------
// grid.x = node tiles of 64, grid.y = outdim half (64 dims); block 256 threads.
// LDS: both W halves (64x128 each, 32KB each = 64KB total).
// thread (tx=t&15, ty=t>>4) computes 4 nodes x 4 outdims; per-lane k-stagger
// spreads LDS banks and global row loads.

__global__ __launch_bounds__(256) void sage_gemm_kernel(
    const float* __restrict__ M, const float* __restrict__ X,
    const float* __restrict__ Wl, const float* __restrict__ Wr,
    const float* __restrict__ b, float* __restrict__ H, int n) {
  __shared__ float sWl[64 * 128];
  __shared__ float sWr[64 * 128];
  int t = threadIdx.x;
  int half = blockIdx.y;  // 0 or 1
  int tile = blockIdx.x;

  // stage W halves, coalesced
  for (int idx = t; idx < 2048; idx += 256) {
    int j = idx >> 5;      // 0..63
    int k4 = idx & 31;     // float4 index
    *(float4*)(sWl + j * 128 + k4 * 4) =
        *(const float4*)(Wl + (size_t)(half * 64 + j) * 128 + k4 * 4);
    *(float4*)(sWr + j * 128 + k4 * 4) =
        *(const float4*)(Wr + (size_t)(half * 64 + j) * 128 + k4 * 4);
  }
  __syncthreads();

  int tx = t & 15;
  int ty = t >> 4;
  int i0 = tile * 64 + ty * 4;
  float acc[4][4];
#pragma unroll
  for (int a = 0; a < 4; ++a)
#pragma unroll
    for (int c = 0; c < 4; ++c) acc[a][c] = 0.f;

  int k0 = tx * 4;
#pragma unroll 4
  for (int s = 0; s < 32; ++s) {
    int k = (k0 + s * 4) & 127;
    float4 m4[4], x4[4];
#pragma unroll
    for (int ii = 0; ii < 4; ++ii) {
      int i = i0 + ii;
      int ic = (i < n) ? i : 0;
      m4[ii] = *(const float4*)(M + (size_t)ic * 128 + k);
      x4[ii] = *(const float4*)(X + (size_t)ic * 128 + k);
    }
#pragma unroll
    for (int jj = 0; jj < 4; ++jj) {
      int j = tx * 4 + jj;
      float4 wl = *(const float4*)(sWl + j * 128 + k);
      float4 wr = *(const float4*)(sWr + j * 128 + k);
#pragma unroll
      for (int ii = 0; ii < 4; ++ii) {
        acc[ii][jj] += m4[ii].x * wl.x + m4[ii].y * wl.y + m4[ii].z * wl.z + m4[ii].w * wl.w +
                       x4[ii].x * wr.x + x4[ii].y * wr.y + x4[ii].z * wr.z + x4[ii].w * wr.w;
      }
    }
  }

  float4 b4 = *(const float4*)(b + half * 64 + tx * 4);
#pragma unroll
  for (int ii = 0; ii < 4; ++ii) {
    int i = i0 + ii;
    if (i < n) {
      float4 o;
      o.x = fmaxf(acc[ii][0] + b4.x, 0.f);
      o.y = fmaxf(acc[ii][1] + b4.y, 0.f);
      o.z = fmaxf(acc[ii][2] + b4.z, 0.f);
      o.w = fmaxf(acc[ii][3] + b4.w, 0.f);
      *(float4*)(H + (size_t)i * 128 + half * 64 + tx * 4) = o;
    }
  }
}

// ---------------- global mean pool (batch sorted, int32) ----------------

__global__ void pool_kernel(const float* __restrict__ H, const int* __restrict__ batch,
                            float* __restrict__ gsum, float* __restrict__ gcnt, int n) {
  int t = threadIdx.x;  // 128 threads, dim = t
  int base = blockIdx.x * 256;
  int endn = base + 256 < n ? base + 256 : n;
  if (base >= n) return;
  int cur = batch[base];
  float acc = 0.f;
  int cnt = 0;
  for (int nd = base; nd < endn; ++nd) {
    int g = batch[nd];
    if (g != cur) {
      atomicAdd(&gsum[cur * 128 + t], acc);
      if (t == 0) atomicAdd(&gcnt[cur], (float)cnt);
      acc = 0.f;
      cnt = 0;
      cur = g;
    }
    acc += H[(size_t)nd * 128 + t];
    cnt++;
  }
  atomicAdd(&gsum[cur * 128 + t], acc);
  if (t == 0) atomicAdd(&gcnt[cur], (float)cnt);
}

__global__ void finalize_kernel(const float* __restrict__ gsum, const float* __restrict__ gcnt,
                                float* __restrict__ out, int total) {
  int i = blockIdx.x * 256 + threadIdx.x;
  if (i < total) {
    int g = i >> 7;
    out[i] = gsum[i] / fmaxf(gcnt[g], 1.f);
  }
}

// ---------------- host ----------------

extern "C" void kernel_launch(void* const* d_in, const int* in_sizes, int n_in,
                              void* d_out, int out_size, void* d_ws, size_t ws_size,
                              hipStream_t stream) {
  const float* x = (const float*)d_in[0];
  const int* ei = (const int*)d_in[1];     // int inputs arrive as int32
  const int* batch = (const int*)d_in[2];  // int32
  const float* Wl0 = (const float*)d_in[3];
  const float* Wr0 = (const float*)d_in[4];
  const float* b0 = (const float*)d_in[5];
  const float* Wl1 = (const float*)d_in[6];
  const float* Wr1 = (const float*)d_in[7];
  const float* b1 = (const float*)d_in[8];
  const float* Wl2 = (const float*)d_in[9];
  const float* Wr2 = (const float*)d_in[10];
  const float* b2 = (const float*)d_in[11];
  float* out = (float*)d_out;

  const int N = in_sizes[0] / 128;
  const int E = in_sizes[1] / 2;
  const int G = out_size / 128;

  // workspace carve-up (~161 MB total)
  char* ws = (char*)d_ws;
  size_t off = 0;
  auto carve = [&](size_t bytes) {
    size_t o = align_up(off, 512);
    off = o + bytes;
    return (void*)(ws + o);
  };
  int* deg = (int*)carve((size_t)N * 4);  // reused as cursor after scan
  int* row_ptr = (int*)carve(((size_t)N + 1) * 4);
  int* blk = (int*)carve(1024 * 4);
  int* col = (int*)carve((size_t)E * 4);
  float* M = (float*)carve((size_t)N * 128 * 4);
  float* hA = (float*)carve((size_t)N * 128 * 4);
  float* hB = (float*)carve((size_t)N * 128 * 4);
  float* gsum = (float*)carve((size_t)G * 128 * 4);
  float* gcnt = (float*)carve((size_t)G * 4);
  (void)ws_size;

  // ---- CSR build ----
  hipMemsetAsync(deg, 0, (size_t)N * 4, stream);
  int egrid = (E + 255) / 256;
  hipLaunchKernelGGL(hist_kernel, dim3(egrid), dim3(256), 0, stream, ei, deg, E);
  int nb = (N + 1023) / 1024;
  hipLaunchKernelGGL(scan_blocks_kernel, dim3(nb), dim3(1024), 0, stream, deg, row_ptr, blk, N);
  hipLaunchKernelGGL(scan_top_kernel, dim3(1), dim3(64), 0, stream, blk, nb);
  hipLaunchKernelGGL(scan_add_kernel, dim3(nb), dim3(1024), 0, stream, row_ptr, blk, N);
  int ngrid = (N + 255) / 256;
  hipLaunchKernelGGL(cursor_kernel, dim3(ngrid), dim3(256), 0, stream, row_ptr, deg, N);
  hipLaunchKernelGGL(scatter_kernel, dim3(egrid), dim3(256), 0, stream, ei, deg, col, E);

  int agrid = (N + 3) / 4;
  dim3 ggrid((N + 63) / 64, 2);

  // ---- layer 0: x -> hA ----
  hipLaunchKernelGGL(aggr_kernel, dim3(agrid), dim3(256), 0, stream, x, row_ptr, col, M, N);
  hipLaunchKernelGGL(sage_gemm_kernel, ggrid, dim3(256), 0, stream, M, x, Wl0, Wr0, b0, hA, N);
  // ---- layer 1: hA -> hB ----
  hipLaunchKernelGGL(aggr_kernel, dim3(agrid), dim3(256), 0, stream, hA, row_ptr, col, M, N);
  hipLaunchKernelGGL(sage_gemm_kernel, ggrid, dim3(256), 0, stream, M, hA, Wl1, Wr1, b1, hB, N);
  // ---- layer 2: hB -> hA ----
  hipLaunchKernelGGL(aggr_kernel, dim3(agrid), dim3(256), 0, stream, hB, row_ptr, col, M, N);
  hipLaunchKernelGGL(sage_gemm_kernel, ggrid, dim3(256), 0, stream, M, hB, Wl2, Wr2, b2, hA, N);

  // ---- pool ----
  hipMemsetAsync(gsum, 0, (size_t)G * 128 * 4, stream);
  hipMemsetAsync(gcnt, 0, (size_t)G * 4, stream);
  int pgrid = (N + 255) / 256;
  hipLaunchKernelGGL(pool_kernel, dim3(pgrid), dim3(128), 0, stream, hA, batch, gsum, gcnt, N);
  int fgrid = (out_size + 255) / 256;
  hipLaunchKernelGGL(finalize_kernel, dim3(fgrid), dim3(256), 0, stream, gsum, gcnt, out, out_size);
}

// Round 3
// 895.898 us; speedup vs baseline: 1.4799x; 1.4799x over previous
//
#include <hip/hip_runtime.h>

static inline size_t align_up(size_t x, size_t a) { return (x + a - 1) & ~(a - 1); }

using bf16x8 = __attribute__((ext_vector_type(8))) short;
using f32x4 = __attribute__((ext_vector_type(4))) float;

__device__ inline ushort f2bf(float x) {  // RNE float->bf16
  unsigned u = __float_as_uint(x);
  unsigned r = (u + 0x7fffu + ((u >> 16) & 1u)) >> 16;
  return (ushort)r;
}
__device__ inline float bf2f(ushort h) { return __uint_as_float((unsigned)h << 16); }

// ---------------- CSR build (edge_index int32: ei[0..E)=src, ei[E..2E)=dst) ----------------

__global__ void hist_kernel(const int* __restrict__ ei, int* __restrict__ deg, int E) {
  int e = blockIdx.x * 256 + threadIdx.x;
  if (e < E) atomicAdd(&deg[ei[(size_t)E + e]], 1);
}

__global__ void scan_blocks_kernel(const int* __restrict__ deg, int* __restrict__ row_ptr,
                                   int* __restrict__ blk, int n) {
  __shared__ int sb[1024];
  int t = threadIdx.x;
  int i = blockIdx.x * 1024 + t;
  int v = (i < n) ? deg[i] : 0;
  sb[t] = v;
  __syncthreads();
  int acc = v;
  for (int d = 1; d < 1024; d <<= 1) {
    int add = (t >= d) ? sb[t - d] : 0;
    __syncthreads();
    acc += add;
    sb[t] = acc;
    __syncthreads();
  }
  if (i < n) row_ptr[i + 1] = acc;
  if (t == 1023) blk[blockIdx.x] = acc;
  if (i == 0) row_ptr[0] = 0;
}

__global__ void scan_top_kernel(int* blk, int nb) {
  if (threadIdx.x == 0 && blockIdx.x == 0) {
    int s = 0;
    for (int b = 0; b < nb; ++b) { int v = blk[b]; blk[b] = s; s += v; }
  }
}

__global__ void scan_add_kernel(int* __restrict__ row_ptr, const int* __restrict__ blk, int n) {
  int i = blockIdx.x * 1024 + threadIdx.x;
  if (i < n) row_ptr[i + 1] += blk[i >> 10];
}

__global__ void cursor_kernel(const int* __restrict__ row_ptr, int* __restrict__ cursor, int n) {
  int i = blockIdx.x * 256 + threadIdx.x;
  if (i < n) cursor[i] = row_ptr[i];
}

__global__ void scatter_kernel(const int* __restrict__ ei, int* __restrict__ cursor,
                               int* __restrict__ col, int E) {
  int e = blockIdx.x * 256 + threadIdx.x;
  if (e < E) {
    int d = ei[(size_t)E + e];
    int slot = atomicAdd(&cursor[d], 1);
    col[slot] = ei[e];
  }
}

// ---------------- conversions ----------------

__global__ void convx_kernel(const float* __restrict__ x, ushort* __restrict__ xh,
                             ushort* __restrict__ xl, int total4) {
  int i = blockIdx.x * 256 + threadIdx.x;
  if (i >= total4) return;
  float4 v = *(const float4*)(x + (size_t)i * 4);
  ushort4 h, l;
  h.x = f2bf(v.x); l.x = f2bf(v.x - bf2f(h.x));
  h.y = f2bf(v.y); l.y = f2bf(v.y - bf2f(h.y));
  h.z = f2bf(v.z); l.z = f2bf(v.z - bf2f(h.z));
  h.w = f2bf(v.w); l.w = f2bf(v.w - bf2f(h.w));
  *(ushort4*)(xh + (size_t)i * 4) = h;
  *(ushort4*)(xl + (size_t)i * 4) = l;
}

// weight planes per layer: [Wl_h(16384), Wl_l, Wr_h, Wr_l] => 65536 ushorts/layer
__global__ void wconv_kernel(const float* Wl0, const float* Wr0, const float* Wl1,
                             const float* Wr1, const float* Wl2, const float* Wr2,
                             ushort* __restrict__ Wp) {
  int m = blockIdx.y;  // 0..5
  const float* src = (m == 0) ? Wl0 : (m == 1) ? Wr0 : (m == 2) ? Wl1
                   : (m == 3) ? Wr1 : (m == 4) ? Wl2 : Wr2;
  int layer = m >> 1, part = m & 1;
  ushort* dh = Wp + layer * 65536 + part * 32768;
  ushort* dl = dh + 16384;
  int i = blockIdx.x * 256 + threadIdx.x;  // 4096 threads x 4 elems = 16384
  float4 v = *(const float4*)(src + (size_t)i * 4);
  ushort4 h, l;
  h.x = f2bf(v.x); l.x = f2bf(v.x - bf2f(h.x));
  h.y = f2bf(v.y); l.y = f2bf(v.y - bf2f(h.y));
  h.z = f2bf(v.z); l.z = f2bf(v.z - bf2f(h.z));
  h.w = f2bf(v.w); l.w = f2bf(v.w - bf2f(h.w));
  *(ushort4*)(dh + (size_t)i * 4) = h;
  *(ushort4*)(dl + (size_t)i * 4) = l;
}

// ---------------- mean aggregation on hi/lo planes ----------------
// wave per node, lane covers 2 dims; unroll 4 edges for MLP

__global__ void aggr2_kernel(const ushort* __restrict__ Xh, const ushort* __restrict__ Xl,
                             const int* __restrict__ row_ptr, const int* __restrict__ col,
                             ushort* __restrict__ Mh, ushort* __restrict__ Ml, int n) {
  int node = blockIdx.x * 4 + (threadIdx.x >> 6);
  if (node >= n) return;
  int lane = threadIdx.x & 63;
  int d0 = lane * 2;
  int beg = row_ptr[node], end = row_ptr[node + 1];
  float s0 = 0.f, s1 = 0.f, t0 = 0.f, t1 = 0.f;
  int e = beg;
  for (; e + 4 <= end; e += 4) {
    int c0 = col[e], c1 = col[e + 1], c2 = col[e + 2], c3 = col[e + 3];
    ushort2 h0 = *(const ushort2*)(Xh + (size_t)c0 * 128 + d0);
    ushort2 l0 = *(const ushort2*)(Xl + (size_t)c0 * 128 + d0);
    ushort2 h1 = *(const ushort2*)(Xh + (size_t)c1 * 128 + d0);
    ushort2 l1 = *(const ushort2*)(Xl + (size_t)c1 * 128 + d0);
    ushort2 h2 = *(const ushort2*)(Xh + (size_t)c2 * 128 + d0);
    ushort2 l2 = *(const ushort2*)(Xl + (size_t)c2 * 128 + d0);
    ushort2 h3 = *(const ushort2*)(Xh + (size_t)c3 * 128 + d0);
    ushort2 l3 = *(const ushort2*)(Xl + (size_t)c3 * 128 + d0);
    s0 += (bf2f(h0.x) + bf2f(l0.x)) + (bf2f(h1.x) + bf2f(l1.x));
    s1 += (bf2f(h0.y) + bf2f(l0.y)) + (bf2f(h1.y) + bf2f(l1.y));
    t0 += (bf2f(h2.x) + bf2f(l2.x)) + (bf2f(h3.x) + bf2f(l3.x));
    t1 += (bf2f(h2.y) + bf2f(l2.y)) + (bf2f(h3.y) + bf2f(l3.y));
  }
  for (; e < end; ++e) {
    int c = col[e];
    ushort2 h = *(const ushort2*)(Xh + (size_t)c * 128 + d0);
    ushort2 l = *(const ushort2*)(Xl + (size_t)c * 128 + d0);
    s0 += bf2f(h.x) + bf2f(l.x);
    s1 += bf2f(h.y) + bf2f(l.y);
  }
  s0 += t0;
  s1 += t1;
  int d = end - beg;
  float inv = 1.0f / (float)(d > 1 ? d : 1);
  float m0 = s0 * inv, m1 = s1 * inv;
  ushort2 oh, ol;
  oh.x = f2bf(m0); ol.x = f2bf(m0 - bf2f(oh.x));
  oh.y = f2bf(m1); ol.y = f2bf(m1 - bf2f(oh.y));
  *(ushort2*)(Mh + (size_t)node * 128 + d0) = oh;
  *(ushort2*)(Ml + (size_t)node * 128 + d0) = ol;
}

// ---------------- split-bf16 MFMA GEMM ----------------
// H[i][j] = relu( sum_k M[i][k]*Wl[j][k] + sum_k X[i][k]*Wr[j][k] + b[j] )
// A,B given as hi/lo bf16 planes; 3 MFMAs per (hi+lo)x(hi+lo) product (drop lo*lo).
// Block: 256 thr = 4 waves in 2x2; wave tile 64 rows x 64 cols; block 128x128.
// No LDS, no barriers; frags loaded straight from global (L1/L2-resident).

__global__ __launch_bounds__(256, 2) void gemm_kernel(
    const ushort* __restrict__ Mh, const ushort* __restrict__ Ml,
    const ushort* __restrict__ Xh, const ushort* __restrict__ Xl,
    const ushort* __restrict__ Wp, const float* __restrict__ bias,
    ushort* __restrict__ Hh, ushort* __restrict__ Hl, float* __restrict__ Hf,
    int n, int out_f32) {
  int t = threadIdx.x;
  int lane = t & 63;
  int li = lane & 15, lg = lane >> 4;
  int w = t >> 6;
  int m0 = blockIdx.x * 128 + (w >> 1) * 64;
  int n0 = (w & 1) * 64;

  f32x4 acc[4][4] = {};

  int rows[4];
#pragma unroll
  for (int mf = 0; mf < 4; ++mf) {
    int r = m0 + mf * 16 + li;
    rows[mf] = (r < n) ? r : (n - 1);
  }

#pragma unroll
  for (int ph = 0; ph < 2; ++ph) {
    const ushort* Ah = ph ? Xh : Mh;
    const ushort* Al = ph ? Xl : Ml;
    const ushort* Wh = Wp + (ph ? 32768 : 0);
    const ushort* Wlo = Wh + 16384;
#pragma unroll
    for (int s = 0; s < 4; ++s) {
      int k0 = s * 32 + lg * 8;
      bf16x8 ah[4], al[4], bh[4], bl[4];
#pragma unroll
      for (int mf = 0; mf < 4; ++mf) {
        ah[mf] = *(const bf16x8*)(Ah + (size_t)rows[mf] * 128 + k0);
        al[mf] = *(const bf16x8*)(Al + (size_t)rows[mf] * 128 + k0);
      }
#pragma unroll
      for (int nf = 0; nf < 4; ++nf) {
        int wr = n0 + nf * 16 + li;
        bh[nf] = *(const bf16x8*)(Wh + wr * 128 + k0);
        bl[nf] = *(const bf16x8*)(Wlo + wr * 128 + k0);
      }
#pragma unroll
      for (int mf = 0; mf < 4; ++mf)
#pragma unroll
        for (int nf = 0; nf < 4; ++nf) {
          acc[mf][nf] = __builtin_amdgcn_mfma_f32_16x16x32_bf16(ah[mf], bh[nf], acc[mf][nf], 0, 0, 0);
          acc[mf][nf] = __builtin_amdgcn_mfma_f32_16x16x32_bf16(ah[mf], bl[nf], acc[mf][nf], 0, 0, 0);
          acc[mf][nf] = __builtin_amdgcn_mfma_f32_16x16x32_bf16(al[mf], bh[nf], acc[mf][nf], 0, 0, 0);
        }
    }
  }

#pragma unroll
  for (int nf = 0; nf < 4; ++nf) {
    int colj = n0 + nf * 16 + li;
    float bj = bias[colj];
#pragma unroll
    for (int mf = 0; mf < 4; ++mf) {
#pragma unroll
      for (int r = 0; r < 4; ++r) {
        int row = m0 + mf * 16 + lg * 4 + r;
        if (row < n) {
          float v = fmaxf(acc[mf][nf][r] + bj, 0.f);
          size_t o = (size_t)row * 128 + colj;
          if (out_f32) {
            Hf[o] = v;
          } else {
            ushort h = f2bf(v);
            Hh[o] = h;
            Hl[o] = f2bf(v - bf2f(h));
          }
        }
      }
    }
  }
}

// ---------------- global mean pool (batch sorted, int32) ----------------

__global__ void pool_kernel(const float* __restrict__ H, const int* __restrict__ batch,
                            float* __restrict__ gsum, float* __restrict__ gcnt, int n) {
  int t = threadIdx.x;  // 128 threads, dim = t
  int base = blockIdx.x * 256;
  int endn = base + 256 < n ? base + 256 : n;
  if (base >= n) return;
  int cur = batch[base];
  float acc = 0.f;
  int cnt = 0;
  for (int nd = base; nd < endn; ++nd) {
    int g = batch[nd];
    if (g != cur) {
      atomicAdd(&gsum[cur * 128 + t], acc);
      if (t == 0) atomicAdd(&gcnt[cur], (float)cnt);
      acc = 0.f;
      cnt = 0;
      cur = g;
    }
    acc += H[(size_t)nd * 128 + t];
    cnt++;
  }
  atomicAdd(&gsum[cur * 128 + t], acc);
  if (t == 0) atomicAdd(&gcnt[cur], (float)cnt);
}

__global__ void finalize_kernel(const float* __restrict__ gsum, const float* __restrict__ gcnt,
                                float* __restrict__ out, int total) {
  int i = blockIdx.x * 256 + threadIdx.x;
  if (i < total) {
    int g = i >> 7;
    out[i] = gsum[i] / fmaxf(gcnt[g], 1.f);
  }
}

// ---------------- host ----------------

extern "C" void kernel_launch(void* const* d_in, const int* in_sizes, int n_in,
                              void* d_out, int out_size, void* d_ws, size_t ws_size,
                              hipStream_t stream) {
  const float* x = (const float*)d_in[0];
  const int* ei = (const int*)d_in[1];
  const int* batch = (const int*)d_in[2];
  const float* Wl0 = (const float*)d_in[3];
  const float* Wr0 = (const float*)d_in[4];
  const float* b0 = (const float*)d_in[5];
  const float* Wl1 = (const float*)d_in[6];
  const float* Wr1 = (const float*)d_in[7];
  const float* b1 = (const float*)d_in[8];
  const float* Wl2 = (const float*)d_in[9];
  const float* Wr2 = (const float*)d_in[10];
  const float* b2 = (const float*)d_in[11];
  float* out = (float*)d_out;

  const int N = in_sizes[0] / 128;
  const int E = in_sizes[1] / 2;
  const int G = out_size / 128;
  const size_t NF = (size_t)N * 128;

  char* ws = (char*)d_ws;
  size_t off = 0;
  auto carve = [&](size_t bytes) {
    size_t o = align_up(off, 512);
    off = o + bytes;
    return (void*)(ws + o);
  };
  int* deg = (int*)carve((size_t)N * 4);  // reused as scatter cursor
  int* row_ptr = (int*)carve(((size_t)N + 1) * 4);
  int* blk = (int*)carve(1024 * 4);
  int* col = (int*)carve((size_t)E * 4);
  ushort* P0 = (ushort*)carve(NF * 4);  // hi plane, then lo plane
  ushort* P1 = (ushort*)carve(NF * 4);
  ushort* M = (ushort*)carve(NF * 4);
  ushort* Wp = (ushort*)carve(3 * 65536 * 2);
  float* gsum = (float*)carve((size_t)G * 128 * 4);
  float* gcnt = (float*)carve((size_t)G * 4);
  (void)ws_size;

  ushort* P0h = P0, *P0l = P0 + NF;
  ushort* P1h = P1, *P1l = P1 + NF;
  ushort* Mh = M, *Ml = M + NF;
  float* Hf = (float*)P1;  // final fp32 H aliases P1 (dead after layer-1 GEMM)

  // ---- CSR build ----
  hipMemsetAsync(deg, 0, (size_t)N * 4, stream);
  int egrid = (E + 255) / 256;
  hipLaunchKernelGGL(hist_kernel, dim3(egrid), dim3(256), 0, stream, ei, deg, E);
  int nb = (N + 1023) / 1024;
  hipLaunchKernelGGL(scan_blocks_kernel, dim3(nb), dim3(1024), 0, stream, deg, row_ptr, blk, N);
  hipLaunchKernelGGL(scan_top_kernel, dim3(1), dim3(64), 0, stream, blk, nb);
  hipLaunchKernelGGL(scan_add_kernel, dim3(nb), dim3(1024), 0, stream, row_ptr, blk, N);
  int ngrid = (N + 255) / 256;
  hipLaunchKernelGGL(cursor_kernel, dim3(ngrid), dim3(256), 0, stream, row_ptr, deg, N);
  hipLaunchKernelGGL(scatter_kernel, dim3(egrid), dim3(256), 0, stream, ei, deg, col, E);

  // ---- conversions ----
  int cgrid = (int)((NF / 4 + 255) / 256);
  hipLaunchKernelGGL(convx_kernel, dim3(cgrid), dim3(256), 0, stream, x, P0h, P0l, (int)(NF / 4));
  hipLaunchKernelGGL(wconv_kernel, dim3(16, 6), dim3(256), 0, stream, Wl0, Wr0, Wl1, Wr1, Wl2,
                     Wr2, Wp);

  int agrid = (N + 3) / 4;
  int ggrid = (N + 127) / 128;

  // ---- layer 0: P0 -> P1 ----
  hipLaunchKernelGGL(aggr2_kernel, dim3(agrid), dim3(256), 0, stream, P0h, P0l, row_ptr, col, Mh,
                     Ml, N);
  hipLaunchKernelGGL(gemm_kernel, dim3(ggrid), dim3(256), 0, stream, Mh, Ml, P0h, P0l, Wp, b0,
                     P1h, P1l, (float*)nullptr, N, 0);
  // ---- layer 1: P1 -> P0 ----
  hipLaunchKernelGGL(aggr2_kernel, dim3(agrid), dim3(256), 0, stream, P1h, P1l, row_ptr, col, Mh,
                     Ml, N);
  hipLaunchKernelGGL(gemm_kernel, dim3(ggrid), dim3(256), 0, stream, Mh, Ml, P1h, P1l, Wp + 65536,
                     b1, P0h, P0l, (float*)nullptr, N, 0);
  // ---- layer 2: P0 -> Hf (fp32, aliases P1) ----
  hipLaunchKernelGGL(aggr2_kernel, dim3(agrid), dim3(256), 0, stream, P0h, P0l, row_ptr, col, Mh,
                     Ml, N);
  hipLaunchKernelGGL(gemm_kernel, dim3(ggrid), dim3(256), 0, stream, Mh, Ml, P0h, P0l,
                     Wp + 2 * 65536, b2, (ushort*)nullptr, (ushort*)nullptr, Hf, N, 1);

  // ---- pool ----
  hipMemsetAsync(gsum, 0, (size_t)G * 128 * 4, stream);
  hipMemsetAsync(gcnt, 0, (size_t)G * 4, stream);
  int pgrid = (N + 255) / 256;
  hipLaunchKernelGGL(pool_kernel, dim3(pgrid), dim3(128), 0, stream, Hf, batch, gsum, gcnt, N);
  int fgrid = (out_size + 255) / 256;
  hipLaunchKernelGGL(finalize_kernel, dim3(fgrid), dim3(256), 0, stream, gsum, gcnt, out, out_size);
}

// Round 4
// 802.790 us; speedup vs baseline: 1.6515x; 1.1160x over previous
//
#include <hip/hip_runtime.h>

static inline size_t align_up(size_t x, size_t a) { return (x + a - 1) & ~(a - 1); }

using bf16x8 = __attribute__((ext_vector_type(8))) short;
using f32x4 = __attribute__((ext_vector_type(4))) float;

__device__ inline ushort f2bf(float x) {  // RNE float->bf16
  unsigned u = __float_as_uint(x);
  return (ushort)((u + 0x7fffu + ((u >> 16) & 1u)) >> 16);
}
__device__ inline float bf2f(ushort h) { return __uint_as_float((unsigned)h << 16); }
// interleaved element: u = h | (l<<16); value = bf2f(h)+bf2f(l)
__device__ inline float unpack_sum(unsigned u) {
  return __uint_as_float(u << 16) + __uint_as_float(u & 0xffff0000u);
}
__device__ inline unsigned pack_hl(float v) {
  ushort h = f2bf(v);
  ushort l = f2bf(v - bf2f(h));
  return (unsigned)h | ((unsigned)l << 16);
}

// ---------------- CSR build (edge_index int32: ei[0..E)=src, ei[E..2E)=dst) ----------------

__global__ void hist_kernel(const int* __restrict__ ei, int* __restrict__ deg, int E) {
  int e = blockIdx.x * 256 + threadIdx.x;
  if (e < E) atomicAdd(&deg[ei[(size_t)E + e]], 1);
}

__global__ void scan_blocks_kernel(const int* __restrict__ deg, int* __restrict__ row_ptr,
                                   int* __restrict__ blk, int n) {
  __shared__ int sb[1024];
  int t = threadIdx.x;
  int i = blockIdx.x * 1024 + t;
  int v = (i < n) ? deg[i] : 0;
  sb[t] = v;
  __syncthreads();
  int acc = v;
  for (int d = 1; d < 1024; d <<= 1) {
    int add = (t >= d) ? sb[t - d] : 0;
    __syncthreads();
    acc += add;
    sb[t] = acc;
    __syncthreads();
  }
  if (i < n) row_ptr[i + 1] = acc;
  if (t == 1023) blk[blockIdx.x] = acc;
  if (i == 0) row_ptr[0] = 0;
}

__global__ void scan_top_kernel(int* blk, int nb) {
  if (threadIdx.x == 0 && blockIdx.x == 0) {
    int s = 0;
    for (int b = 0; b < nb; ++b) { int v = blk[b]; blk[b] = s; s += v; }
  }
}

__global__ void scan_add_kernel(int* __restrict__ row_ptr, const int* __restrict__ blk, int n) {
  int i = blockIdx.x * 1024 + threadIdx.x;
  if (i < n) row_ptr[i + 1] += blk[i >> 10];
}

__global__ void cursor_kernel(const int* __restrict__ row_ptr, int* __restrict__ cursor, int n) {
  int i = blockIdx.x * 256 + threadIdx.x;
  if (i < n) cursor[i] = row_ptr[i];
}

__global__ void scatter_kernel(const int* __restrict__ ei, int* __restrict__ cursor,
                               int* __restrict__ col, int E) {
  int e = blockIdx.x * 256 + threadIdx.x;
  if (e < E) {
    int d = ei[(size_t)E + e];
    int slot = atomicAdd(&cursor[d], 1);
    col[slot] = ei[e];
  }
}

// ---------------- conversions ----------------

// x fp32 -> interleaved hi/lo plane (one uint per element)
__global__ void convx_kernel(const float* __restrict__ x, unsigned* __restrict__ X, int total4) {
  int i = blockIdx.x * 256 + threadIdx.x;
  if (i >= total4) return;
  float4 v = *(const float4*)(x + (size_t)i * 4);
  uint4 o;
  o.x = pack_hl(v.x);
  o.y = pack_hl(v.y);
  o.z = pack_hl(v.z);
  o.w = pack_hl(v.w);
  *(uint4*)(X + (size_t)i * 4) = o;
}

// W [128 out][128 k] fp32 -> swizzled fragment-native bf16 planes (hi, lo separate)
// dst(j,k) = (j>>4)*2048 + ((k>>3)*16 + (j&15))*8 + (k&7)
// per layer: [Wl_h(16384) Wl_l Wr_h Wr_l] = 65536 ushorts
__global__ void wconv_kernel(const float* Wl0, const float* Wr0, const float* Wl1,
                             const float* Wr1, const float* Wl2, const float* Wr2,
                             ushort* __restrict__ Wp) {
  int m = blockIdx.y;  // 0..5
  const float* src = (m == 0) ? Wl0 : (m == 1) ? Wr0 : (m == 2) ? Wl1
                   : (m == 3) ? Wr1 : (m == 4) ? Wl2 : Wr2;
  int layer = m >> 1, part = m & 1;
  ushort* dh = Wp + layer * 65536 + part * 32768;
  ushort* dl = dh + 16384;
  int i = blockIdx.x * 256 + threadIdx.x;  // 0..4095
  int j = i >> 5;          // out-dim (B row) 0..127
  int k = (i & 31) * 4;    // k 0..124
  float4 v = *(const float4*)(src + (size_t)j * 128 + k);
  int doff = ((j >> 4) << 11) + (((k >> 3) << 4) + (j & 15)) * 8 + (k & 7);
  ushort4 h, l;
  h.x = f2bf(v.x); l.x = f2bf(v.x - bf2f(h.x));
  h.y = f2bf(v.y); l.y = f2bf(v.y - bf2f(h.y));
  h.z = f2bf(v.z); l.z = f2bf(v.z - bf2f(h.z));
  h.w = f2bf(v.w); l.w = f2bf(v.w - bf2f(h.w));
  *(ushort4*)(dh + doff) = h;
  *(ushort4*)(dl + doff) = l;
}

// ---------------- mean aggregation on interleaved plane ----------------
// wave per node; lane covers 2 dims (uint2 = 8B, 512B/row coalesced)

__global__ void aggr_kernel(const unsigned* __restrict__ X, const int* __restrict__ row_ptr,
                            const int* __restrict__ col, unsigned* __restrict__ M, int n) {
  int node = blockIdx.x * 4 + (threadIdx.x >> 6);
  if (node >= n) return;
  int lane = threadIdx.x & 63;
  int k0 = lane * 2;
  int beg = row_ptr[node], end = row_ptr[node + 1];
  float s0 = 0.f, s1 = 0.f, t0 = 0.f, t1 = 0.f;
  int e = beg;
  for (; e + 4 <= end; e += 4) {
    int c0 = col[e], c1 = col[e + 1], c2 = col[e + 2], c3 = col[e + 3];
    uint2 u0 = *(const uint2*)(X + (size_t)c0 * 128 + k0);
    uint2 u1 = *(const uint2*)(X + (size_t)c1 * 128 + k0);
    uint2 u2 = *(const uint2*)(X + (size_t)c2 * 128 + k0);
    uint2 u3 = *(const uint2*)(X + (size_t)c3 * 128 + k0);
    s0 += unpack_sum(u0.x) + unpack_sum(u1.x);
    s1 += unpack_sum(u0.y) + unpack_sum(u1.y);
    t0 += unpack_sum(u2.x) + unpack_sum(u3.x);
    t1 += unpack_sum(u2.y) + unpack_sum(u3.y);
  }
  for (; e < end; ++e) {
    int c = col[e];
    uint2 u = *(const uint2*)(X + (size_t)c * 128 + k0);
    s0 += unpack_sum(u.x);
    s1 += unpack_sum(u.y);
  }
  s0 += t0;
  s1 += t1;
  int d = end - beg;
  float inv = 1.0f / (float)(d > 1 ? d : 1);
  uint2 o;
  o.x = pack_hl(s0 * inv);
  o.y = pack_hl(s1 * inv);
  *(uint2*)(M + (size_t)node * 128 + k0) = o;
}

// ---------------- split-bf16 MFMA GEMM ----------------
// H = relu(M @ Wl^T + X @ Wr^T + b). A-side: interleaved hi/lo planes (unpack in reg).
// B-side: swizzled fragment-native planes (coalesced 1KB/wave loads).
// Wave tile 32x64; block = 2x2 waves = 64 rows x 128 cols; grid = ceil(N/64).

__global__ __launch_bounds__(256) void gemm_kernel(
    const unsigned* __restrict__ A0, const unsigned* __restrict__ A1,
    const ushort* __restrict__ Wp, const float* __restrict__ bias,
    unsigned* __restrict__ Hout, float* __restrict__ Hf, int n, int out_f32) {
  int t = threadIdx.x;
  int lane = t & 63;
  int li = lane & 15, lg = lane >> 4;
  int w = t >> 6;
  int m0 = blockIdx.x * 64 + (w >> 1) * 32;
  int n0 = (w & 1) * 64;

  int rows[2];
#pragma unroll
  for (int mf = 0; mf < 2; ++mf) {
    int r = m0 + mf * 16 + li;
    rows[mf] = (r < n) ? r : (n - 1);
  }

  f32x4 acc[2][4] = {};

  union U4 { unsigned u[4]; bf16x8 v; };

#pragma unroll
  for (int ph = 0; ph < 2; ++ph) {
    const unsigned* A = ph ? A1 : A0;
    const ushort* Wh = Wp + ph * 32768;
#pragma unroll
    for (int s = 0; s < 4; ++s) {
      int kg = s * 4 + lg;
      int k0 = kg * 8;
      // B fragments (coalesced)
      bf16x8 bh[4], bl[4];
#pragma unroll
      for (int nf = 0; nf < 4; ++nf) {
        const ushort* bp = Wh + (((n0 >> 4) + nf) << 11) + (kg * 16 + li) * 8;
        bh[nf] = *(const bf16x8*)bp;
        bl[nf] = *(const bf16x8*)(bp + 16384);
      }
      // A fragments: 32B interleaved per lane, unpack hi/lo
      bf16x8 ah[2], al[2];
#pragma unroll
      for (int mf = 0; mf < 2; ++mf) {
        const unsigned* ap = A + (size_t)rows[mf] * 128 + k0;
        uint4 u0 = *(const uint4*)ap;
        uint4 u1 = *(const uint4*)(ap + 4);
        U4 xh, xl;
        xh.u[0] = (u0.x & 0xffffu) | (u0.y << 16);
        xl.u[0] = (u0.x >> 16) | (u0.y & 0xffff0000u);
        xh.u[1] = (u0.z & 0xffffu) | (u0.w << 16);
        xl.u[1] = (u0.z >> 16) | (u0.w & 0xffff0000u);
        xh.u[2] = (u1.x & 0xffffu) | (u1.y << 16);
        xl.u[2] = (u1.x >> 16) | (u1.y & 0xffff0000u);
        xh.u[3] = (u1.z & 0xffffu) | (u1.w << 16);
        xl.u[3] = (u1.z >> 16) | (u1.w & 0xffff0000u);
        ah[mf] = xh.v;
        al[mf] = xl.v;
      }
#pragma unroll
      for (int mf = 0; mf < 2; ++mf)
#pragma unroll
        for (int nf = 0; nf < 4; ++nf) {
          acc[mf][nf] = __builtin_amdgcn_mfma_f32_16x16x32_bf16(ah[mf], bh[nf], acc[mf][nf], 0, 0, 0);
          acc[mf][nf] = __builtin_amdgcn_mfma_f32_16x16x32_bf16(ah[mf], bl[nf], acc[mf][nf], 0, 0, 0);
          acc[mf][nf] = __builtin_amdgcn_mfma_f32_16x16x32_bf16(al[mf], bh[nf], acc[mf][nf], 0, 0, 0);
        }
    }
  }

#pragma unroll
  for (int nf = 0; nf < 4; ++nf) {
    int colj = n0 + nf * 16 + li;
    float bj = bias[colj];
#pragma unroll
    for (int mf = 0; mf < 2; ++mf) {
#pragma unroll
      for (int r = 0; r < 4; ++r) {
        int row = m0 + mf * 16 + lg * 4 + r;
        if (row < n) {
          float v = fmaxf(acc[mf][nf][r] + bj, 0.f);
          size_t o = (size_t)row * 128 + colj;
          if (out_f32) Hf[o] = v;
          else Hout[o] = pack_hl(v);
        }
      }
    }
  }
}

// ---------------- global mean pool (batch sorted, int32) ----------------

__global__ void pool_kernel(const float* __restrict__ H, const int* __restrict__ batch,
                            float* __restrict__ gsum, float* __restrict__ gcnt, int n) {
  int t = threadIdx.x;  // 128 threads, dim = t
  int base = blockIdx.x * 256;
  int endn = base + 256 < n ? base + 256 : n;
  if (base >= n) return;
  int cur = batch[base];
  float acc = 0.f;
  int cnt = 0;
  for (int nd = base; nd < endn; ++nd) {
    int g = batch[nd];
    if (g != cur) {
      atomicAdd(&gsum[cur * 128 + t], acc);
      if (t == 0) atomicAdd(&gcnt[cur], (float)cnt);
      acc = 0.f;
      cnt = 0;
      cur = g;
    }
    acc += H[(size_t)nd * 128 + t];
    cnt++;
  }
  atomicAdd(&gsum[cur * 128 + t], acc);
  if (t == 0) atomicAdd(&gcnt[cur], (float)cnt);
}

__global__ void finalize_kernel(const float* __restrict__ gsum, const float* __restrict__ gcnt,
                                float* __restrict__ out, int total) {
  int i = blockIdx.x * 256 + threadIdx.x;
  if (i < total) {
    int g = i >> 7;
    out[i] = gsum[i] / fmaxf(gcnt[g], 1.f);
  }
}

// ---------------- host ----------------

extern "C" void kernel_launch(void* const* d_in, const int* in_sizes, int n_in,
                              void* d_out, int out_size, void* d_ws, size_t ws_size,
                              hipStream_t stream) {
  const float* x = (const float*)d_in[0];
  const int* ei = (const int*)d_in[1];
  const int* batch = (const int*)d_in[2];
  const float* Wl0 = (const float*)d_in[3];
  const float* Wr0 = (const float*)d_in[4];
  const float* b0 = (const float*)d_in[5];
  const float* Wl1 = (const float*)d_in[6];
  const float* Wr1 = (const float*)d_in[7];
  const float* b1 = (const float*)d_in[8];
  const float* Wl2 = (const float*)d_in[9];
  const float* Wr2 = (const float*)d_in[10];
  const float* b2 = (const float*)d_in[11];
  float* out = (float*)d_out;

  const int N = in_sizes[0] / 128;
  const int E = in_sizes[1] / 2;
  const int G = out_size / 128;
  const size_t NF = (size_t)N * 128;

  char* ws = (char*)d_ws;
  size_t off = 0;
  auto carve = [&](size_t bytes) {
    size_t o = align_up(off, 512);
    off = o + bytes;
    return (void*)(ws + o);
  };
  int* deg = (int*)carve((size_t)N * 4);  // reused as scatter cursor
  int* row_ptr = (int*)carve(((size_t)N + 1) * 4);
  int* blk = (int*)carve(1024 * 4);
  int* col = (int*)carve((size_t)E * 4);
  unsigned* P0 = (unsigned*)carve(NF * 4);  // interleaved hi/lo planes
  unsigned* P1 = (unsigned*)carve(NF * 4);
  unsigned* M = (unsigned*)carve(NF * 4);
  ushort* Wp = (ushort*)carve(3 * 65536 * 2);
  float* gsum = (float*)carve((size_t)G * 128 * 4);
  float* gcnt = (float*)carve((size_t)G * 4);
  (void)ws_size;

  float* Hf = (float*)P1;  // final fp32 H aliases P1 (dead after layer-1 GEMM)

  // ---- CSR build ----
  hipMemsetAsync(deg, 0, (size_t)N * 4, stream);
  int egrid = (E + 255) / 256;
  hipLaunchKernelGGL(hist_kernel, dim3(egrid), dim3(256), 0, stream, ei, deg, E);
  int nb = (N + 1023) / 1024;
  hipLaunchKernelGGL(scan_blocks_kernel, dim3(nb), dim3(1024), 0, stream, deg, row_ptr, blk, N);
  hipLaunchKernelGGL(scan_top_kernel, dim3(1), dim3(64), 0, stream, blk, nb);
  hipLaunchKernelGGL(scan_add_kernel, dim3(nb), dim3(1024), 0, stream, row_ptr, blk, N);
  int ngrid = (N + 255) / 256;
  hipLaunchKernelGGL(cursor_kernel, dim3(ngrid), dim3(256), 0, stream, row_ptr, deg, N);
  hipLaunchKernelGGL(scatter_kernel, dim3(egrid), dim3(256), 0, stream, ei, deg, col, E);

  // ---- conversions ----
  int cgrid = (int)((NF / 4 + 255) / 256);
  hipLaunchKernelGGL(convx_kernel, dim3(cgrid), dim3(256), 0, stream, x, P0, (int)(NF / 4));
  hipLaunchKernelGGL(wconv_kernel, dim3(16, 6), dim3(256), 0, stream, Wl0, Wr0, Wl1, Wr1, Wl2,
                     Wr2, Wp);

  int agrid = (N + 3) / 4;
  int ggrid = (N + 63) / 64;

  // ---- layer 0: P0 -> P1 ----
  hipLaunchKernelGGL(aggr_kernel, dim3(agrid), dim3(256), 0, stream, P0, row_ptr, col, M, N);
  hipLaunchKernelGGL(gemm_kernel, dim3(ggrid), dim3(256), 0, stream, M, P0, Wp, b0, P1,
                     (float*)nullptr, N, 0);
  // ---- layer 1: P1 -> P0 ----
  hipLaunchKernelGGL(aggr_kernel, dim3(agrid), dim3(256), 0, stream, P1, row_ptr, col, M, N);
  hipLaunchKernelGGL(gemm_kernel, dim3(ggrid), dim3(256), 0, stream, M, P1, Wp + 65536, b1, P0,
                     (float*)nullptr, N, 0);
  // ---- layer 2: P0 -> Hf (fp32, aliases P1) ----
  hipLaunchKernelGGL(aggr_kernel, dim3(agrid), dim3(256), 0, stream, P0, row_ptr, col, M, N);
  hipLaunchKernelGGL(gemm_kernel, dim3(ggrid), dim3(256), 0, stream, M, P0, Wp + 2 * 65536, b2,
                     (unsigned*)nullptr, Hf, N, 1);

  // ---- pool ----
  hipMemsetAsync(gsum, 0, (size_t)G * 128 * 4, stream);
  hipMemsetAsync(gcnt, 0, (size_t)G * 4, stream);
  int pgrid = (N + 255) / 256;
  hipLaunchKernelGGL(pool_kernel, dim3(pgrid), dim3(128), 0, stream, Hf, batch, gsum, gcnt, N);
  int fgrid = (out_size + 255) / 256;
  hipLaunchKernelGGL(finalize_kernel, dim3(fgrid), dim3(256), 0, stream, gsum, gcnt, out, out_size);
}

// Round 5
// 645.967 us; speedup vs baseline: 2.0525x; 1.2428x over previous
//
#include <hip/hip_runtime.h>

static inline size_t align_up(size_t x, size_t a) { return (x + a - 1) & ~(a - 1); }

using bf16x8 = __attribute__((ext_vector_type(8))) short;
using f32x4 = __attribute__((ext_vector_type(4))) float;

__device__ inline ushort f2bf(float x) {  // RNE float->bf16
  unsigned u = __float_as_uint(x);
  return (ushort)((u + 0x7fffu + ((u >> 16) & 1u)) >> 16);
}
__device__ inline float bf2f(ushort h) { return __uint_as_float((unsigned)h << 16); }
// interleaved element: u = h | (l<<16); value = bf2f(h)+bf2f(l)
__device__ inline float unpack_sum(unsigned u) {
  return __uint_as_float(u << 16) + __uint_as_float(u & 0xffff0000u);
}
__device__ inline unsigned pack_hl(float v) {
  ushort h = f2bf(v);
  ushort l = f2bf(v - bf2f(h));
  return (unsigned)h | ((unsigned)l << 16);
}

// ================= bucketed CSR build =================
// buckets of 256 consecutive dst nodes; K = ceil(N/256) (<=1024)

__global__ void bhist_kernel(const int* __restrict__ ei, int* __restrict__ bcnt, int E, int K) {
  __shared__ int lh[1024];
  int t = threadIdx.x;
  for (int i = t; i < 1024; i += 256) lh[i] = 0;
  __syncthreads();
  int base = blockIdx.x * 4096;
#pragma unroll
  for (int r = 0; r < 16; ++r) {
    int e = base + r * 256 + t;
    if (e < E) atomicAdd(&lh[ei[(size_t)E + e] >> 8], 1);
  }
  __syncthreads();
  for (int i = t; i < K; i += 256)
    if (lh[i]) atomicAdd(&bcnt[i], lh[i]);
}

__global__ void bscan_kernel(const int* __restrict__ bcnt, int* __restrict__ bbase,
                             int* __restrict__ bcur, int K) {
  __shared__ int sb[1024];
  int t = threadIdx.x;  // 1024
  int v = (t < K) ? bcnt[t] : 0;
  sb[t] = v;
  __syncthreads();
  int acc = v;
  for (int d = 1; d < 1024; d <<= 1) {
    int add = (t >= d) ? sb[t - d] : 0;
    __syncthreads();
    acc += add;
    sb[t] = acc;
    __syncthreads();
  }
  if (t < K) {
    int ex = acc - v;  // exclusive
    bbase[t] = ex;
    bcur[t] = ex;
  }
}

// scatter edges into bucket-major (src,dst) pairs; per-(block,bucket) contiguous runs
__global__ void bscatter_kernel(const int* __restrict__ ei, int* __restrict__ bcur,
                                int2* __restrict__ ebuf, int E) {
  __shared__ int lh[1024];
  __shared__ int lbase[1024];
  int t = threadIdx.x;
  for (int i = t; i < 1024; i += 256) lh[i] = 0;
  __syncthreads();
  int base = blockIdx.x * 4096;
  int src[16], dst[16];
#pragma unroll
  for (int r = 0; r < 16; ++r) {
    int e = base + r * 256 + t;
    if (e < E) {
      src[r] = ei[e];
      dst[r] = ei[(size_t)E + e];
      atomicAdd(&lh[dst[r] >> 8], 1);
    } else {
      dst[r] = -1;
    }
  }
  __syncthreads();
  for (int i = t; i < 1024; i += 256) {
    int c = lh[i];
    lbase[i] = c ? atomicAdd(&bcur[i], c) : 0;
    lh[i] = 0;
  }
  __syncthreads();
#pragma unroll
  for (int r = 0; r < 16; ++r) {
    if (dst[r] >= 0) {
      int b = dst[r] >> 8;
      int rank = atomicAdd(&lh[b], 1);
      ebuf[lbase[b] + rank] = make_int2(src[r], dst[r]);
    }
  }
}

// per bucket: LDS deg count + in-block scan -> row_ptr; LDS-cursor scatter -> col
__global__ void fine_kernel(const int* __restrict__ bbase, const int2* __restrict__ ebuf,
                            int* __restrict__ row_ptr, int* __restrict__ col, int E, int N,
                            int K) {
  int bkt = blockIdx.x;
  int nb0 = bkt << 8;
  int t = threadIdx.x;  // 256
  int base = bbase[bkt];
  int endi = (bkt + 1 < K) ? bbase[bkt + 1] : E;
  __shared__ int sdeg[256];
  __shared__ int cur[256];
  sdeg[t] = 0;
  __syncthreads();
  for (int i = base + t; i < endi; i += 256) atomicAdd(&sdeg[ebuf[i].y & 255], 1);
  __syncthreads();
  int v = sdeg[t];
  int acc = v;
  for (int d = 1; d < 256; d <<= 1) {
    int add = (t >= d) ? sdeg[t - d] : 0;
    __syncthreads();
    acc += add;
    sdeg[t] = acc;
    __syncthreads();
  }
  int gp = base + (acc - v);  // exclusive prefix
  if (nb0 + t < N) row_ptr[nb0 + t] = gp;
  if (bkt == K - 1 && t == 0) row_ptr[N] = E;
  cur[t] = gp;
  __syncthreads();
  for (int i = base + t; i < endi; i += 256) {
    int2 sd = ebuf[i];
    int slot = atomicAdd(&cur[sd.y & 255], 1);
    col[slot] = sd.x;
  }
}

// ================= conversions =================

__global__ void convx_kernel(const float* __restrict__ x, unsigned* __restrict__ X, int total4) {
  int i = blockIdx.x * 256 + threadIdx.x;
  if (i >= total4) return;
  float4 v = *(const float4*)(x + (size_t)i * 4);
  uint4 o;
  o.x = pack_hl(v.x);
  o.y = pack_hl(v.y);
  o.z = pack_hl(v.z);
  o.w = pack_hl(v.w);
  *(uint4*)(X + (size_t)i * 4) = o;
}

// W [128 out][128 k] fp32 -> swizzled fragment-native bf16 planes (hi, lo separate)
// dst(j,k) = (j>>4)*2048 + ((k>>3)*16 + (j&15))*8 + (k&7)
__global__ void wconv_kernel(const float* Wl0, const float* Wr0, const float* Wl1,
                             const float* Wr1, const float* Wl2, const float* Wr2,
                             ushort* __restrict__ Wp) {
  int m = blockIdx.y;  // 0..5
  const float* src = (m == 0) ? Wl0 : (m == 1) ? Wr0 : (m == 2) ? Wl1
                   : (m == 3) ? Wr1 : (m == 4) ? Wl2 : Wr2;
  int layer = m >> 1, part = m & 1;
  ushort* dh = Wp + layer * 65536 + part * 32768;
  ushort* dl = dh + 16384;
  int i = blockIdx.x * 256 + threadIdx.x;  // 0..4095
  int j = i >> 5;
  int k = (i & 31) * 4;
  float4 v = *(const float4*)(src + (size_t)j * 128 + k);
  int doff = ((j >> 4) << 11) + (((k >> 3) << 4) + (j & 15)) * 8 + (k & 7);
  ushort4 h, l;
  h.x = f2bf(v.x); l.x = f2bf(v.x - bf2f(h.x));
  h.y = f2bf(v.y); l.y = f2bf(v.y - bf2f(h.y));
  h.z = f2bf(v.z); l.z = f2bf(v.z - bf2f(h.z));
  h.w = f2bf(v.w); l.w = f2bf(v.w - bf2f(h.w));
  *(ushort4*)(dh + doff) = h;
  *(ushort4*)(dl + doff) = l;
}

// ================= mean aggregation (interleaved hi/lo plane) =================

__global__ void aggr_kernel(const unsigned* __restrict__ X, const int* __restrict__ row_ptr,
                            const int* __restrict__ col, unsigned* __restrict__ M, int n) {
  int node = blockIdx.x * 4 + (threadIdx.x >> 6);
  if (node >= n) return;
  int lane = threadIdx.x & 63;
  int k0 = lane * 2;
  int beg = row_ptr[node], end = row_ptr[node + 1];
  float s0 = 0.f, s1 = 0.f, t0 = 0.f, t1 = 0.f;
  int e = beg;
  for (; e + 4 <= end; e += 4) {
    int c0 = col[e], c1 = col[e + 1], c2 = col[e + 2], c3 = col[e + 3];
    uint2 u0 = *(const uint2*)(X + (size_t)c0 * 128 + k0);
    uint2 u1 = *(const uint2*)(X + (size_t)c1 * 128 + k0);
    uint2 u2 = *(const uint2*)(X + (size_t)c2 * 128 + k0);
    uint2 u3 = *(const uint2*)(X + (size_t)c3 * 128 + k0);
    s0 += unpack_sum(u0.x) + unpack_sum(u1.x);
    s1 += unpack_sum(u0.y) + unpack_sum(u1.y);
    t0 += unpack_sum(u2.x) + unpack_sum(u3.x);
    t1 += unpack_sum(u2.y) + unpack_sum(u3.y);
  }
  for (; e < end; ++e) {
    int c = col[e];
    uint2 u = *(const uint2*)(X + (size_t)c * 128 + k0);
    s0 += unpack_sum(u.x);
    s1 += unpack_sum(u.y);
  }
  s0 += t0;
  s1 += t1;
  int d = end - beg;
  float inv = 1.0f / (float)(d > 1 ? d : 1);
  uint2 o;
  o.x = pack_hl(s0 * inv);
  o.y = pack_hl(s1 * inv);
  *(uint2*)(M + (size_t)node * 128 + k0) = o;
}

// ================= split-bf16 MFMA GEMM =================
// H = relu(M @ Wl^T + X @ Wr^T + b); wave tile 32x64; block 64 rows x 128 cols.

__global__ __launch_bounds__(256) void gemm_kernel(
    const unsigned* __restrict__ A0, const unsigned* __restrict__ A1,
    const ushort* __restrict__ Wp, const float* __restrict__ bias,
    unsigned* __restrict__ Hout, float* __restrict__ Hf, int n, int out_f32) {
  int t = threadIdx.x;
  int lane = t & 63;
  int li = lane & 15, lg = lane >> 4;
  int w = t >> 6;
  int m0 = blockIdx.x * 64 + (w >> 1) * 32;
  int n0 = (w & 1) * 64;

  int rows[2];
#pragma unroll
  for (int mf = 0; mf < 2; ++mf) {
    int r = m0 + mf * 16 + li;
    rows[mf] = (r < n) ? r : (n - 1);
  }

  f32x4 acc[2][4] = {};
  union U4 { unsigned u[4]; bf16x8 v; };

#pragma unroll
  for (int ph = 0; ph < 2; ++ph) {
    const unsigned* A = ph ? A1 : A0;
    const ushort* Wh = Wp + ph * 32768;
#pragma unroll
    for (int s = 0; s < 4; ++s) {
      int kg = s * 4 + lg;
      int k0 = kg * 8;
      bf16x8 bh[4], bl[4];
#pragma unroll
      for (int nf = 0; nf < 4; ++nf) {
        const ushort* bp = Wh + (((n0 >> 4) + nf) << 11) + (kg * 16 + li) * 8;
        bh[nf] = *(const bf16x8*)bp;
        bl[nf] = *(const bf16x8*)(bp + 16384);
      }
      bf16x8 ah[2], al[2];
#pragma unroll
      for (int mf = 0; mf < 2; ++mf) {
        const unsigned* ap = A + (size_t)rows[mf] * 128 + k0;
        uint4 u0 = *(const uint4*)ap;
        uint4 u1 = *(const uint4*)(ap + 4);
        U4 xh, xl;
        xh.u[0] = (u0.x & 0xffffu) | (u0.y << 16);
        xl.u[0] = (u0.x >> 16) | (u0.y & 0xffff0000u);
        xh.u[1] = (u0.z & 0xffffu) | (u0.w << 16);
        xl.u[1] = (u0.z >> 16) | (u0.w & 0xffff0000u);
        xh.u[2] = (u1.x & 0xffffu) | (u1.y << 16);
        xl.u[2] = (u1.x >> 16) | (u1.y & 0xffff0000u);
        xh.u[3] = (u1.z & 0xffffu) | (u1.w << 16);
        xl.u[3] = (u1.z >> 16) | (u1.w & 0xffff0000u);
        ah[mf] = xh.v;
        al[mf] = xl.v;
      }
#pragma unroll
      for (int mf = 0; mf < 2; ++mf)
#pragma unroll
        for (int nf = 0; nf < 4; ++nf) {
          acc[mf][nf] = __builtin_amdgcn_mfma_f32_16x16x32_bf16(ah[mf], bh[nf], acc[mf][nf], 0, 0, 0);
          acc[mf][nf] = __builtin_amdgcn_mfma_f32_16x16x32_bf16(ah[mf], bl[nf], acc[mf][nf], 0, 0, 0);
          acc[mf][nf] = __builtin_amdgcn_mfma_f32_16x16x32_bf16(al[mf], bh[nf], acc[mf][nf], 0, 0, 0);
        }
    }
  }

#pragma unroll
  for (int nf = 0; nf < 4; ++nf) {
    int colj = n0 + nf * 16 + li;
    float bj = bias[colj];
#pragma unroll
    for (int mf = 0; mf < 2; ++mf) {
#pragma unroll
      for (int r = 0; r < 4; ++r) {
        int row = m0 + mf * 16 + lg * 4 + r;
        if (row < n) {
          float v = fmaxf(acc[mf][nf][r] + bj, 0.f);
          size_t o = (size_t)row * 128 + colj;
          if (out_f32) Hf[o] = v;
          else Hout[o] = pack_hl(v);
        }
      }
    }
  }
}

// ================= global mean pool (batch sorted, int32) =================

__global__ void pool_kernel(const float* __restrict__ H, const int* __restrict__ batch,
                            float* __restrict__ gsum, float* __restrict__ gcnt, int n) {
  int t = threadIdx.x;  // 128
  int base = blockIdx.x * 256;
  int endn = base + 256 < n ? base + 256 : n;
  if (base >= n) return;
  int cur = batch[base];
  float acc = 0.f;
  int cnt = 0;
  for (int nd = base; nd < endn; ++nd) {
    int g = batch[nd];
    if (g != cur) {
      atomicAdd(&gsum[cur * 128 + t], acc);
      if (t == 0) atomicAdd(&gcnt[cur], (float)cnt);
      acc = 0.f;
      cnt = 0;
      cur = g;
    }
    acc += H[(size_t)nd * 128 + t];
    cnt++;
  }
  atomicAdd(&gsum[cur * 128 + t], acc);
  if (t == 0) atomicAdd(&gcnt[cur], (float)cnt);
}

__global__ void finalize_kernel(const float* __restrict__ gsum, const float* __restrict__ gcnt,
                                float* __restrict__ out, int total) {
  int i = blockIdx.x * 256 + threadIdx.x;
  if (i < total) {
    int g = i >> 7;
    out[i] = gsum[i] / fmaxf(gcnt[g], 1.f);
  }
}

// ================= host =================

extern "C" void kernel_launch(void* const* d_in, const int* in_sizes, int n_in,
                              void* d_out, int out_size, void* d_ws, size_t ws_size,
                              hipStream_t stream) {
  const float* x = (const float*)d_in[0];
  const int* ei = (const int*)d_in[1];
  const int* batch = (const int*)d_in[2];
  const float* Wl0 = (const float*)d_in[3];
  const float* Wr0 = (const float*)d_in[4];
  const float* b0 = (const float*)d_in[5];
  const float* Wl1 = (const float*)d_in[6];
  const float* Wr1 = (const float*)d_in[7];
  const float* b1 = (const float*)d_in[8];
  const float* Wl2 = (const float*)d_in[9];
  const float* Wr2 = (const float*)d_in[10];
  const float* b2 = (const float*)d_in[11];
  float* out = (float*)d_out;

  const int N = in_sizes[0] / 128;
  const int E = in_sizes[1] / 2;
  const int G = out_size / 128;
  const int K = (N + 255) >> 8;  // buckets of 256 nodes
  const size_t NF = (size_t)N * 128;

  char* ws = (char*)d_ws;
  size_t off = 0;
  auto carve = [&](size_t bytes) {
    size_t o = align_up(off, 512);
    off = o + bytes;
    return (void*)(ws + o);
  };
  int* row_ptr = (int*)carve(((size_t)N + 1) * 4);
  int* bcnt = (int*)carve(1024 * 4);
  int* bbase = (int*)carve(1024 * 4);
  int* bcur = (int*)carve(1024 * 4);
  int* col = (int*)carve((size_t)E * 4);
  unsigned* P0 = (unsigned*)carve(NF * 4);
  unsigned* P1 = (unsigned*)carve(NF * 4);
  unsigned* M = (unsigned*)carve(NF * 4);
  ushort* Wp = (ushort*)carve(3 * 65536 * 2);
  float* gsum = (float*)carve((size_t)G * 128 * 4);
  float* gcnt = (float*)carve((size_t)G * 4);
  (void)ws_size;

  int2* ebuf = (int2*)M;   // ebuf dead before first aggr writes M
  float* Hf = (float*)P1;  // final fp32 H aliases P1

  // ---- bucketed CSR build ----
  hipMemsetAsync(bcnt, 0, 1024 * 4, stream);
  int cgrid_e = (E + 4095) / 4096;
  hipLaunchKernelGGL(bhist_kernel, dim3(cgrid_e), dim3(256), 0, stream, ei, bcnt, E, K);
  hipLaunchKernelGGL(bscan_kernel, dim3(1), dim3(1024), 0, stream, bcnt, bbase, bcur, K);
  hipLaunchKernelGGL(bscatter_kernel, dim3(cgrid_e), dim3(256), 0, stream, ei, bcur, ebuf, E);
  hipLaunchKernelGGL(fine_kernel, dim3(K), dim3(256), 0, stream, bbase, ebuf, row_ptr, col, E, N,
                     K);

  // ---- conversions ----
  int cgrid = (int)((NF / 4 + 255) / 256);
  hipLaunchKernelGGL(convx_kernel, dim3(cgrid), dim3(256), 0, stream, x, P0, (int)(NF / 4));
  hipLaunchKernelGGL(wconv_kernel, dim3(16, 6), dim3(256), 0, stream, Wl0, Wr0, Wl1, Wr1, Wl2,
                     Wr2, Wp);

  int agrid = (N + 3) / 4;
  int ggrid = (N + 63) / 64;

  // ---- layer 0: P0 -> P1 ----
  hipLaunchKernelGGL(aggr_kernel, dim3(agrid), dim3(256), 0, stream, P0, row_ptr, col, M, N);
  hipLaunchKernelGGL(gemm_kernel, dim3(ggrid), dim3(256), 0, stream, M, P0, Wp, b0, P1,
                     (float*)nullptr, N, 0);
  // ---- layer 1: P1 -> P0 ----
  hipLaunchKernelGGL(aggr_kernel, dim3(agrid), dim3(256), 0, stream, P1, row_ptr, col, M, N);
  hipLaunchKernelGGL(gemm_kernel, dim3(ggrid), dim3(256), 0, stream, M, P1, Wp + 65536, b1, P0,
                     (float*)nullptr, N, 0);
  // ---- layer 2: P0 -> Hf ----
  hipLaunchKernelGGL(aggr_kernel, dim3(agrid), dim3(256), 0, stream, P0, row_ptr, col, M, N);
  hipLaunchKernelGGL(gemm_kernel, dim3(ggrid), dim3(256), 0, stream, M, P0, Wp + 2 * 65536, b2,
                     (unsigned*)nullptr, Hf, N, 1);

  // ---- pool ----
  hipMemsetAsync(gsum, 0, (size_t)G * 128 * 4, stream);
  hipMemsetAsync(gcnt, 0, (size_t)G * 4, stream);
  int pgrid = (N + 255) / 256;
  hipLaunchKernelGGL(pool_kernel, dim3(pgrid), dim3(128), 0, stream, Hf, batch, gsum, gcnt, N);
  int fgrid = (out_size + 255) / 256;
  hipLaunchKernelGGL(finalize_kernel, dim3(fgrid), dim3(256), 0, stream, gsum, gcnt, out, out_size);
}

// Round 6
// 503.215 us; speedup vs baseline: 2.6347x; 1.2837x over previous
//
#include <hip/hip_runtime.h>

static inline size_t align_up(size_t x, size_t a) { return (x + a - 1) & ~(a - 1); }

using bf16x8 = __attribute__((ext_vector_type(8))) short;
using f32x4 = __attribute__((ext_vector_type(4))) float;

__device__ inline ushort f2bf(float x) {  // RNE float->bf16
  unsigned u = __float_as_uint(x);
  return (ushort)((u + 0x7fffu + ((u >> 16) & 1u)) >> 16);
}
__device__ inline float bf2f(ushort h) { return __uint_as_float((unsigned)h << 16); }

// ================= bucketed CSR build =================
// buckets of 256 consecutive dst nodes; K = ceil(N/256) (<=1024)

__global__ void bhist_kernel(const int* __restrict__ ei, int* __restrict__ bcnt, int E, int K) {
  __shared__ int lh[1024];
  int t = threadIdx.x;
  for (int i = t; i < 1024; i += 256) lh[i] = 0;
  __syncthreads();
  int base = blockIdx.x * 4096;
#pragma unroll
  for (int r = 0; r < 16; ++r) {
    int e = base + r * 256 + t;
    if (e < E) atomicAdd(&lh[ei[(size_t)E + e] >> 8], 1);
  }
  __syncthreads();
  for (int i = t; i < K; i += 256)
    if (lh[i]) atomicAdd(&bcnt[i], lh[i]);
}

__global__ void bscan_kernel(const int* __restrict__ bcnt, int* __restrict__ bbase,
                             int* __restrict__ bcur, int K) {
  __shared__ int sb[1024];
  int t = threadIdx.x;  // 1024
  int v = (t < K) ? bcnt[t] : 0;
  sb[t] = v;
  __syncthreads();
  int acc = v;
  for (int d = 1; d < 1024; d <<= 1) {
    int add = (t >= d) ? sb[t - d] : 0;
    __syncthreads();
    acc += add;
    sb[t] = acc;
    __syncthreads();
  }
  if (t < K) {
    int ex = acc - v;  // exclusive
    bbase[t] = ex;
    bcur[t] = ex;
  }
}

__global__ void bscatter_kernel(const int* __restrict__ ei, int* __restrict__ bcur,
                                int2* __restrict__ ebuf, int E) {
  __shared__ int lh[1024];
  __shared__ int lbase[1024];
  int t = threadIdx.x;
  for (int i = t; i < 1024; i += 256) lh[i] = 0;
  __syncthreads();
  int base = blockIdx.x * 4096;
  int src[16], dst[16];
#pragma unroll
  for (int r = 0; r < 16; ++r) {
    int e = base + r * 256 + t;
    if (e < E) {
      src[r] = ei[e];
      dst[r] = ei[(size_t)E + e];
      atomicAdd(&lh[dst[r] >> 8], 1);
    } else {
      dst[r] = -1;
    }
  }
  __syncthreads();
  for (int i = t; i < 1024; i += 256) {
    int c = lh[i];
    lbase[i] = c ? atomicAdd(&bcur[i], c) : 0;
    lh[i] = 0;
  }
  __syncthreads();
#pragma unroll
  for (int r = 0; r < 16; ++r) {
    if (dst[r] >= 0) {
      int b = dst[r] >> 8;
      int rank = atomicAdd(&lh[b], 1);
      ebuf[lbase[b] + rank] = make_int2(src[r], dst[r]);
    }
  }
}

__global__ void fine_kernel(const int* __restrict__ bbase, const int2* __restrict__ ebuf,
                            int* __restrict__ row_ptr, int* __restrict__ col, int E, int N,
                            int K) {
  int bkt = blockIdx.x;
  int nb0 = bkt << 8;
  int t = threadIdx.x;  // 256
  int base = bbase[bkt];
  int endi = (bkt + 1 < K) ? bbase[bkt + 1] : E;
  __shared__ int sdeg[256];
  __shared__ int cur[256];
  sdeg[t] = 0;
  __syncthreads();
  for (int i = base + t; i < endi; i += 256) atomicAdd(&sdeg[ebuf[i].y & 255], 1);
  __syncthreads();
  int v = sdeg[t];
  int acc = v;
  for (int d = 1; d < 256; d <<= 1) {
    int add = (t >= d) ? sdeg[t - d] : 0;
    __syncthreads();
    acc += add;
    sdeg[t] = acc;
    __syncthreads();
  }
  int gp = base + (acc - v);  // exclusive prefix
  if (nb0 + t < N) row_ptr[nb0 + t] = gp;
  if (bkt == K - 1 && t == 0) row_ptr[N] = E;
  cur[t] = gp;
  __syncthreads();
  for (int i = base + t; i < endi; i += 256) {
    int2 sd = ebuf[i];
    int slot = atomicAdd(&cur[sd.y & 255], 1);
    col[slot] = sd.x;
  }
}

// ================= conversions =================

// x fp32 -> separate hi/lo bf16 planes
__global__ void convx_kernel(const float* __restrict__ x, ushort* __restrict__ Xh,
                             ushort* __restrict__ Xl, int total4) {
  int i = blockIdx.x * 256 + threadIdx.x;
  if (i >= total4) return;
  float4 v = *(const float4*)(x + (size_t)i * 4);
  ushort4 h, l;
  h.x = f2bf(v.x); l.x = f2bf(v.x - bf2f(h.x));
  h.y = f2bf(v.y); l.y = f2bf(v.y - bf2f(h.y));
  h.z = f2bf(v.z); l.z = f2bf(v.z - bf2f(h.z));
  h.w = f2bf(v.w); l.w = f2bf(v.w - bf2f(h.w));
  *(ushort4*)(Xh + (size_t)i * 4) = h;
  *(ushort4*)(Xl + (size_t)i * 4) = l;
}

// W [128 out][128 k] fp32 -> swizzled fragment-native bf16 planes (hi, lo separate)
// dst(j,k) = (j>>4)*2048 + ((k>>3)*16 + (j&15))*8 + (k&7)
__global__ void wconv_kernel(const float* Wl0, const float* Wr0, const float* Wl1,
                             const float* Wr1, const float* Wl2, const float* Wr2,
                             ushort* __restrict__ Wp) {
  int m = blockIdx.y;  // 0..5
  const float* src = (m == 0) ? Wl0 : (m == 1) ? Wr0 : (m == 2) ? Wl1
                   : (m == 3) ? Wr1 : (m == 4) ? Wl2 : Wr2;
  int layer = m >> 1, part = m & 1;
  ushort* dh = Wp + layer * 65536 + part * 32768;
  ushort* dl = dh + 16384;
  int i = blockIdx.x * 256 + threadIdx.x;  // 0..4095
  int j = i >> 5;
  int k = (i & 31) * 4;
  float4 v = *(const float4*)(src + (size_t)j * 128 + k);
  int doff = ((j >> 4) << 11) + (((k >> 3) << 4) + (j & 15)) * 8 + (k & 7);
  ushort4 h, l;
  h.x = f2bf(v.x); l.x = f2bf(v.x - bf2f(h.x));
  h.y = f2bf(v.y); l.y = f2bf(v.y - bf2f(h.y));
  h.z = f2bf(v.z); l.z = f2bf(v.z - bf2f(h.z));
  h.w = f2bf(v.w); l.w = f2bf(v.w - bf2f(h.w));
  *(ushort4*)(dh + doff) = h;
  *(ushort4*)(dl + doff) = l;
}

// ================= mean aggregation (hi plane only, 256B/row gather) =================

__global__ void aggr_kernel(const ushort* __restrict__ Xh, const int* __restrict__ row_ptr,
                            const int* __restrict__ col, ushort* __restrict__ Mh, int n) {
  int node = blockIdx.x * 4 + (threadIdx.x >> 6);
  if (node >= n) return;
  int lane = threadIdx.x & 63;
  int k0 = lane * 2;
  int beg = row_ptr[node], end = row_ptr[node + 1];
  float s0 = 0.f, s1 = 0.f, t0 = 0.f, t1 = 0.f;
  int e = beg;
  for (; e + 4 <= end; e += 4) {
    int c0 = col[e], c1 = col[e + 1], c2 = col[e + 2], c3 = col[e + 3];
    ushort2 u0 = *(const ushort2*)(Xh + (size_t)c0 * 128 + k0);
    ushort2 u1 = *(const ushort2*)(Xh + (size_t)c1 * 128 + k0);
    ushort2 u2 = *(const ushort2*)(Xh + (size_t)c2 * 128 + k0);
    ushort2 u3 = *(const ushort2*)(Xh + (size_t)c3 * 128 + k0);
    s0 += bf2f(u0.x) + bf2f(u1.x);
    s1 += bf2f(u0.y) + bf2f(u1.y);
    t0 += bf2f(u2.x) + bf2f(u3.x);
    t1 += bf2f(u2.y) + bf2f(u3.y);
  }
  for (; e < end; ++e) {
    int c = col[e];
    ushort2 u = *(const ushort2*)(Xh + (size_t)c * 128 + k0);
    s0 += bf2f(u.x);
    s1 += bf2f(u.y);
  }
  s0 += t0;
  s1 += t1;
  int d = end - beg;
  float inv = 1.0f / (float)(d > 1 ? d : 1);
  ushort2 o;
  o.x = f2bf(s0 * inv);
  o.y = f2bf(s1 * inv);
  *(ushort2*)(Mh + (size_t)node * 128 + k0) = o;
}

// ================= split-bf16 MFMA GEMM =================
// H = relu(M @ Wl^T + X @ Wr^T + b).
// M-branch: hi-only (2 MFMA/product); X-branch: hi/lo (3 MFMA/product).
// B-side: swizzled fragment-native planes (coalesced). Wave tile 32x64; block 64x128.

__global__ __launch_bounds__(256) void gemm_kernel(
    const ushort* __restrict__ Mh, const ushort* __restrict__ Xh,
    const ushort* __restrict__ Xl, const ushort* __restrict__ Wp,
    const float* __restrict__ bias, ushort* __restrict__ Hh, ushort* __restrict__ Hl,
    float* __restrict__ Hf, int n, int out_f32) {
  int t = threadIdx.x;
  int lane = t & 63;
  int li = lane & 15, lg = lane >> 4;
  int w = t >> 6;
  int m0 = blockIdx.x * 64 + (w >> 1) * 32;
  int n0 = (w & 1) * 64;

  int rows[2];
#pragma unroll
  for (int mf = 0; mf < 2; ++mf) {
    int r = m0 + mf * 16 + li;
    rows[mf] = (r < n) ? r : (n - 1);
  }

  f32x4 acc[2][4] = {};

  // ---- phase 0: M-branch (hi only) with Wl planes ----
#pragma unroll
  for (int s = 0; s < 4; ++s) {
    int kg = s * 4 + lg;
    int k0 = kg * 8;
    bf16x8 bh[4], bl[4];
#pragma unroll
    for (int nf = 0; nf < 4; ++nf) {
      const ushort* bp = Wp + (((n0 >> 4) + nf) << 11) + (kg * 16 + li) * 8;
      bh[nf] = *(const bf16x8*)bp;
      bl[nf] = *(const bf16x8*)(bp + 16384);
    }
    bf16x8 am[2];
#pragma unroll
    for (int mf = 0; mf < 2; ++mf)
      am[mf] = *(const bf16x8*)(Mh + (size_t)rows[mf] * 128 + k0);
#pragma unroll
    for (int mf = 0; mf < 2; ++mf)
#pragma unroll
      for (int nf = 0; nf < 4; ++nf) {
        acc[mf][nf] = __builtin_amdgcn_mfma_f32_16x16x32_bf16(am[mf], bh[nf], acc[mf][nf], 0, 0, 0);
        acc[mf][nf] = __builtin_amdgcn_mfma_f32_16x16x32_bf16(am[mf], bl[nf], acc[mf][nf], 0, 0, 0);
      }
  }

  // ---- phase 1: X-branch (hi/lo) with Wr planes ----
#pragma unroll
  for (int s = 0; s < 4; ++s) {
    int kg = s * 4 + lg;
    int k0 = kg * 8;
    bf16x8 bh[4], bl[4];
#pragma unroll
    for (int nf = 0; nf < 4; ++nf) {
      const ushort* bp = Wp + 32768 + (((n0 >> 4) + nf) << 11) + (kg * 16 + li) * 8;
      bh[nf] = *(const bf16x8*)bp;
      bl[nf] = *(const bf16x8*)(bp + 16384);
    }
    bf16x8 ah[2], al[2];
#pragma unroll
    for (int mf = 0; mf < 2; ++mf) {
      ah[mf] = *(const bf16x8*)(Xh + (size_t)rows[mf] * 128 + k0);
      al[mf] = *(const bf16x8*)(Xl + (size_t)rows[mf] * 128 + k0);
    }
#pragma unroll
    for (int mf = 0; mf < 2; ++mf)
#pragma unroll
      for (int nf = 0; nf < 4; ++nf) {
        acc[mf][nf] = __builtin_amdgcn_mfma_f32_16x16x32_bf16(ah[mf], bh[nf], acc[mf][nf], 0, 0, 0);
        acc[mf][nf] = __builtin_amdgcn_mfma_f32_16x16x32_bf16(ah[mf], bl[nf], acc[mf][nf], 0, 0, 0);
        acc[mf][nf] = __builtin_amdgcn_mfma_f32_16x16x32_bf16(al[mf], bh[nf], acc[mf][nf], 0, 0, 0);
      }
  }

#pragma unroll
  for (int nf = 0; nf < 4; ++nf) {
    int colj = n0 + nf * 16 + li;
    float bj = bias[colj];
#pragma unroll
    for (int mf = 0; mf < 2; ++mf) {
#pragma unroll
      for (int r = 0; r < 4; ++r) {
        int row = m0 + mf * 16 + lg * 4 + r;
        if (row < n) {
          float v = fmaxf(acc[mf][nf][r] + bj, 0.f);
          size_t o = (size_t)row * 128 + colj;
          if (out_f32) {
            Hf[o] = v;
          } else {
            ushort h = f2bf(v);
            Hh[o] = h;
            Hl[o] = f2bf(v - bf2f(h));
          }
        }
      }
    }
  }
}

// ================= global mean pool (batch sorted, int32) =================

__global__ void pool_kernel(const float* __restrict__ H, const int* __restrict__ batch,
                            float* __restrict__ gsum, float* __restrict__ gcnt, int n) {
  int t = threadIdx.x;  // 128
  int base = blockIdx.x * 256;
  int endn = base + 256 < n ? base + 256 : n;
  if (base >= n) return;
  int cur = batch[base];
  float acc = 0.f;
  int cnt = 0;
  for (int nd = base; nd < endn; ++nd) {
    int g = batch[nd];
    if (g != cur) {
      atomicAdd(&gsum[cur * 128 + t], acc);
      if (t == 0) atomicAdd(&gcnt[cur], (float)cnt);
      acc = 0.f;
      cnt = 0;
      cur = g;
    }
    acc += H[(size_t)nd * 128 + t];
    cnt++;
  }
  atomicAdd(&gsum[cur * 128 + t], acc);
  if (t == 0) atomicAdd(&gcnt[cur], (float)cnt);
}

__global__ void finalize_kernel(const float* __restrict__ gsum, const float* __restrict__ gcnt,
                                float* __restrict__ out, int total) {
  int i = blockIdx.x * 256 + threadIdx.x;
  if (i < total) {
    int g = i >> 7;
    out[i] = gsum[i] / fmaxf(gcnt[g], 1.f);
  }
}

// ================= host =================

extern "C" void kernel_launch(void* const* d_in, const int* in_sizes, int n_in,
                              void* d_out, int out_size, void* d_ws, size_t ws_size,
                              hipStream_t stream) {
  const float* x = (const float*)d_in[0];
  const int* ei = (const int*)d_in[1];
  const int* batch = (const int*)d_in[2];
  const float* Wl0 = (const float*)d_in[3];
  const float* Wr0 = (const float*)d_in[4];
  const float* b0 = (const float*)d_in[5];
  const float* Wl1 = (const float*)d_in[6];
  const float* Wr1 = (const float*)d_in[7];
  const float* b1 = (const float*)d_in[8];
  const float* Wl2 = (const float*)d_in[9];
  const float* Wr2 = (const float*)d_in[10];
  const float* b2 = (const float*)d_in[11];
  float* out = (float*)d_out;

  const int N = in_sizes[0] / 128;
  const int E = in_sizes[1] / 2;
  const int G = out_size / 128;
  const int K = (N + 255) >> 8;
  const size_t NF = (size_t)N * 128;

  char* ws = (char*)d_ws;
  size_t off = 0;
  auto carve = [&](size_t bytes) {
    size_t o = align_up(off, 512);
    off = o + bytes;
    return (void*)(ws + o);
  };
  int* row_ptr = (int*)carve(((size_t)N + 1) * 4);
  int* bcnt = (int*)carve(1024 * 4);
  int* bbase = (int*)carve(1024 * 4);
  int* bcur = (int*)carve(1024 * 4);
  int* col = (int*)carve((size_t)E * 4);
  ushort* P0 = (ushort*)carve(NF * 4);  // hi plane [NF], lo plane [NF]
  ushort* P1 = (ushort*)carve(NF * 4);
  ushort* M = (ushort*)carve(NF * 2);   // hi only
  ushort* Wp = (ushort*)carve(3 * 65536 * 2);
  float* gsum = (float*)carve((size_t)G * 128 * 4);
  float* gcnt = (float*)carve((size_t)G * 4);
  (void)ws_size;

  ushort *P0h = P0, *P0l = P0 + NF;
  ushort *P1h = P1, *P1l = P1 + NF;
  int2* ebuf = (int2*)M;   // ebuf (12.8MB) aliases M (25.6MB); dead before first aggr
  float* Hf = (float*)P1;  // final fp32 H aliases P1 (dead after layer-1 gemm)

  // ---- bucketed CSR build ----
  hipMemsetAsync(bcnt, 0, 1024 * 4, stream);
  int cgrid_e = (E + 4095) / 4096;
  hipLaunchKernelGGL(bhist_kernel, dim3(cgrid_e), dim3(256), 0, stream, ei, bcnt, E, K);
  hipLaunchKernelGGL(bscan_kernel, dim3(1), dim3(1024), 0, stream, bcnt, bbase, bcur, K);
  hipLaunchKernelGGL(bscatter_kernel, dim3(cgrid_e), dim3(256), 0, stream, ei, bcur, ebuf, E);
  hipLaunchKernelGGL(fine_kernel, dim3(K), dim3(256), 0, stream, bbase, ebuf, row_ptr, col, E, N,
                     K);

  // ---- conversions ----
  int cgrid = (int)((NF / 4 + 255) / 256);
  hipLaunchKernelGGL(convx_kernel, dim3(cgrid), dim3(256), 0, stream, x, P0h, P0l, (int)(NF / 4));
  hipLaunchKernelGGL(wconv_kernel, dim3(16, 6), dim3(256), 0, stream, Wl0, Wr0, Wl1, Wr1, Wl2,
                     Wr2, Wp);

  int agrid = (N + 3) / 4;
  int ggrid = (N + 63) / 64;

  // ---- layer 0 ----
  hipLaunchKernelGGL(aggr_kernel, dim3(agrid), dim3(256), 0, stream, P0h, row_ptr, col, M, N);
  hipLaunchKernelGGL(gemm_kernel, dim3(ggrid), dim3(256), 0, stream, M, P0h, P0l, Wp, b0, P1h,
                     P1l, (float*)nullptr, N, 0);
  // ---- layer 1 ----
  hipLaunchKernelGGL(aggr_kernel, dim3(agrid), dim3(256), 0, stream, P1h, row_ptr, col, M, N);
  hipLaunchKernelGGL(gemm_kernel, dim3(ggrid), dim3(256), 0, stream, M, P1h, P1l, Wp + 65536, b1,
                     P0h, P0l, (float*)nullptr, N, 0);
  // ---- layer 2 -> fp32 Hf ----
  hipLaunchKernelGGL(aggr_kernel, dim3(agrid), dim3(256), 0, stream, P0h, row_ptr, col, M, N);
  hipLaunchKernelGGL(gemm_kernel, dim3(ggrid), dim3(256), 0, stream, M, P0h, P0l, Wp + 2 * 65536,
                     b2, (ushort*)nullptr, (ushort*)nullptr, Hf, N, 1);

  // ---- pool ----
  hipMemsetAsync(gsum, 0, (size_t)G * 128 * 4, stream);
  hipMemsetAsync(gcnt, 0, (size_t)G * 4, stream);
  int pgrid = (N + 255) / 256;
  hipLaunchKernelGGL(pool_kernel, dim3(pgrid), dim3(128), 0, stream, Hf, batch, gsum, gcnt, N);
  int fgrid = (out_size + 255) / 256;
  hipLaunchKernelGGL(finalize_kernel, dim3(fgrid), dim3(256), 0, stream, gsum, gcnt, out, out_size);
}

// Round 7
// 434.423 us; speedup vs baseline: 3.0519x; 1.1584x over previous
//
#include <hip/hip_runtime.h>

static inline size_t align_up(size_t x, size_t a) { return (x + a - 1) & ~(a - 1); }

using bf16x8 = __attribute__((ext_vector_type(8))) short;
using f32x4 = __attribute__((ext_vector_type(4))) float;

__device__ inline ushort f2bf(float x) {  // RNE float->bf16
  unsigned u = __float_as_uint(x);
  return (ushort)((u + 0x7fffu + ((u >> 16) & 1u)) >> 16);
}
__device__ inline float bf2f(ushort h) { return __uint_as_float((unsigned)h << 16); }

// ================= bucketed CSR build =================
// buckets of 256 consecutive dst nodes; K = ceil(N/256) (<=1024)

__global__ void bhist_kernel(const int* __restrict__ ei, int* __restrict__ bcnt, int E, int K) {
  __shared__ int lh[1024];
  int t = threadIdx.x;
  for (int i = t; i < 1024; i += 256) lh[i] = 0;
  __syncthreads();
  int base = blockIdx.x * 4096;
#pragma unroll
  for (int r = 0; r < 16; ++r) {
    int e = base + r * 256 + t;
    if (e < E) atomicAdd(&lh[ei[(size_t)E + e] >> 8], 1);
  }
  __syncthreads();
  for (int i = t; i < K; i += 256)
    if (lh[i]) atomicAdd(&bcnt[i], lh[i]);
}

__global__ void bscan_kernel(const int* __restrict__ bcnt, int* __restrict__ bbase,
                             int* __restrict__ bcur, int K) {
  __shared__ int sb[1024];
  int t = threadIdx.x;  // 1024
  int v = (t < K) ? bcnt[t] : 0;
  sb[t] = v;
  __syncthreads();
  int acc = v;
  for (int d = 1; d < 1024; d <<= 1) {
    int add = (t >= d) ? sb[t - d] : 0;
    __syncthreads();
    acc += add;
    sb[t] = acc;
    __syncthreads();
  }
  if (t < K) {
    int ex = acc - v;  // exclusive
    bbase[t] = ex;
    bcur[t] = ex;
  }
}

__global__ void bscatter_kernel(const int* __restrict__ ei, int* __restrict__ bcur,
                                int2* __restrict__ ebuf, int E) {
  __shared__ int lh[1024];
  __shared__ int lbase[1024];
  int t = threadIdx.x;
  for (int i = t; i < 1024; i += 256) lh[i] = 0;
  __syncthreads();
  int base = blockIdx.x * 4096;
  int src[16], dst[16];
#pragma unroll
  for (int r = 0; r < 16; ++r) {
    int e = base + r * 256 + t;
    if (e < E) {
      src[r] = ei[e];
      dst[r] = ei[(size_t)E + e];
      atomicAdd(&lh[dst[r] >> 8], 1);
    } else {
      dst[r] = -1;
    }
  }
  __syncthreads();
  for (int i = t; i < 1024; i += 256) {
    int c = lh[i];
    lbase[i] = c ? atomicAdd(&bcur[i], c) : 0;
    lh[i] = 0;
  }
  __syncthreads();
#pragma unroll
  for (int r = 0; r < 16; ++r) {
    if (dst[r] >= 0) {
      int b = dst[r] >> 8;
      int rank = atomicAdd(&lh[b], 1);
      ebuf[lbase[b] + rank] = make_int2(src[r], dst[r]);
    }
  }
}

__global__ void fine_kernel(const int* __restrict__ bbase, const int2* __restrict__ ebuf,
                            int* __restrict__ row_ptr, int* __restrict__ col, int E, int N,
                            int K) {
  int bkt = blockIdx.x;
  int nb0 = bkt << 8;
  int t = threadIdx.x;  // 256
  int base = bbase[bkt];
  int endi = (bkt + 1 < K) ? bbase[bkt + 1] : E;
  __shared__ int sdeg[256];
  __shared__ int cur[256];
  sdeg[t] = 0;
  __syncthreads();
  for (int i = base + t; i < endi; i += 256) atomicAdd(&sdeg[ebuf[i].y & 255], 1);
  __syncthreads();
  int v = sdeg[t];
  int acc = v;
  for (int d = 1; d < 256; d <<= 1) {
    int add = (t >= d) ? sdeg[t - d] : 0;
    __syncthreads();
    acc += add;
    sdeg[t] = acc;
    __syncthreads();
  }
  int gp = base + (acc - v);  // exclusive prefix
  if (nb0 + t < N) row_ptr[nb0 + t] = gp;
  if (bkt == K - 1 && t == 0) row_ptr[N] = E;
  cur[t] = gp;
  __syncthreads();
  for (int i = base + t; i < endi; i += 256) {
    int2 sd = ebuf[i];
    int slot = atomicAdd(&cur[sd.y & 255], 1);
    col[slot] = sd.x;
  }
}

// ================= conversions =================

// x fp32 -> separate hi/lo bf16 planes
__global__ void convx_kernel(const float* __restrict__ x, ushort* __restrict__ Xh,
                             ushort* __restrict__ Xl, int total4) {
  int i = blockIdx.x * 256 + threadIdx.x;
  if (i >= total4) return;
  float4 v = *(const float4*)(x + (size_t)i * 4);
  ushort4 h, l;
  h.x = f2bf(v.x); l.x = f2bf(v.x - bf2f(h.x));
  h.y = f2bf(v.y); l.y = f2bf(v.y - bf2f(h.y));
  h.z = f2bf(v.z); l.z = f2bf(v.z - bf2f(h.z));
  h.w = f2bf(v.w); l.w = f2bf(v.w - bf2f(h.w));
  *(ushort4*)(Xh + (size_t)i * 4) = h;
  *(ushort4*)(Xl + (size_t)i * 4) = l;
}

// W [128 out][128 k] fp32 -> swizzled fragment-native bf16 planes (hi, lo separate)
// dst(j,k) = (j>>4)*2048 + ((k>>3)*16 + (j&15))*8 + (k&7)
__global__ void wconv_kernel(const float* Wl0, const float* Wr0, const float* Wl1,
                             const float* Wr1, const float* Wl2, const float* Wr2,
                             ushort* __restrict__ Wp) {
  int m = blockIdx.y;  // 0..5
  const float* src = (m == 0) ? Wl0 : (m == 1) ? Wr0 : (m == 2) ? Wl1
                   : (m == 3) ? Wr1 : (m == 4) ? Wl2 : Wr2;
  int layer = m >> 1, part = m & 1;
  ushort* dh = Wp + layer * 65536 + part * 32768;
  ushort* dl = dh + 16384;
  int i = blockIdx.x * 256 + threadIdx.x;  // 0..4095
  int j = i >> 5;
  int k = (i & 31) * 4;
  float4 v = *(const float4*)(src + (size_t)j * 128 + k);
  int doff = ((j >> 4) << 11) + (((k >> 3) << 4) + (j & 15)) * 8 + (k & 7);
  ushort4 h, l;
  h.x = f2bf(v.x); l.x = f2bf(v.x - bf2f(h.x));
  h.y = f2bf(v.y); l.y = f2bf(v.y - bf2f(h.y));
  h.z = f2bf(v.z); l.z = f2bf(v.z - bf2f(h.z));
  h.w = f2bf(v.w); l.w = f2bf(v.w - bf2f(h.w));
  *(ushort4*)(dh + doff) = h;
  *(ushort4*)(dl + doff) = l;
}

// ================= mean aggregation (hi plane only, 256B/row gather) =================

__global__ void aggr_kernel(const ushort* __restrict__ Xh, const int* __restrict__ row_ptr,
                            const int* __restrict__ col, ushort* __restrict__ Mh, int n) {
  int node = blockIdx.x * 4 + (threadIdx.x >> 6);
  if (node >= n) return;
  int lane = threadIdx.x & 63;
  int k0 = lane * 2;
  int beg = row_ptr[node], end = row_ptr[node + 1];
  float s0 = 0.f, s1 = 0.f, t0 = 0.f, t1 = 0.f;
  int e = beg;
  for (; e + 4 <= end; e += 4) {
    int c0 = col[e], c1 = col[e + 1], c2 = col[e + 2], c3 = col[e + 3];
    ushort2 u0 = *(const ushort2*)(Xh + (size_t)c0 * 128 + k0);
    ushort2 u1 = *(const ushort2*)(Xh + (size_t)c1 * 128 + k0);
    ushort2 u2 = *(const ushort2*)(Xh + (size_t)c2 * 128 + k0);
    ushort2 u3 = *(const ushort2*)(Xh + (size_t)c3 * 128 + k0);
    s0 += bf2f(u0.x) + bf2f(u1.x);
    s1 += bf2f(u0.y) + bf2f(u1.y);
    t0 += bf2f(u2.x) + bf2f(u3.x);
    t1 += bf2f(u2.y) + bf2f(u3.y);
  }
  for (; e < end; ++e) {
    int c = col[e];
    ushort2 u = *(const ushort2*)(Xh + (size_t)c * 128 + k0);
    s0 += bf2f(u.x);
    s1 += bf2f(u.y);
  }
  s0 += t0;
  s1 += t1;
  int d = end - beg;
  float inv = 1.0f / (float)(d > 1 ? d : 1);
  ushort2 o;
  o.x = f2bf(s0 * inv);
  o.y = f2bf(s1 * inv);
  *(ushort2*)(Mh + (size_t)node * 128 + k0) = o;
}

// ================= split-bf16 MFMA GEMM =================
// H = relu(M @ Wl^T + X @ Wr^T + b).
// M-branch: hi-only (2 MFMA/product); X-branch: hi/lo (3 MFMA/product).
// B-side: swizzled fragment-native planes (coalesced). Wave tile 32x64; block 64x128.

__global__ __launch_bounds__(256) void gemm_kernel(
    const ushort* __restrict__ Mh, const ushort* __restrict__ Xh,
    const ushort* __restrict__ Xl, const ushort* __restrict__ Wp,
    const float* __restrict__ bias, ushort* __restrict__ Hh, ushort* __restrict__ Hl,
    float* __restrict__ Hf, int n, int out_f32) {
  int t = threadIdx.x;
  int lane = t & 63;
  int li = lane & 15, lg = lane >> 4;
  int w = t >> 6;
  int m0 = blockIdx.x * 64 + (w >> 1) * 32;
  int n0 = (w & 1) * 64;

  int rows[2];
#pragma unroll
  for (int mf = 0; mf < 2; ++mf) {
    int r = m0 + mf * 16 + li;
    rows[mf] = (r < n) ? r : (n - 1);
  }

  f32x4 acc[2][4] = {};

  // ---- phase 0: M-branch (hi only) with Wl planes ----
#pragma unroll
  for (int s = 0; s < 4; ++s) {
    int kg = s * 4 + lg;
    int k0 = kg * 8;
    bf16x8 bh[4], bl[4];
#pragma unroll
    for (int nf = 0; nf < 4; ++nf) {
      const ushort* bp = Wp + (((n0 >> 4) + nf) << 11) + (kg * 16 + li) * 8;
      bh[nf] = *(const bf16x8*)bp;
      bl[nf] = *(const bf16x8*)(bp + 16384);
    }
    bf16x8 am[2];
#pragma unroll
    for (int mf = 0; mf < 2; ++mf)
      am[mf] = *(const bf16x8*)(Mh + (size_t)rows[mf] * 128 + k0);
#pragma unroll
    for (int mf = 0; mf < 2; ++mf)
#pragma unroll
      for (int nf = 0; nf < 4; ++nf) {
        acc[mf][nf] = __builtin_amdgcn_mfma_f32_16x16x32_bf16(am[mf], bh[nf], acc[mf][nf], 0, 0, 0);
        acc[mf][nf] = __builtin_amdgcn_mfma_f32_16x16x32_bf16(am[mf], bl[nf], acc[mf][nf], 0, 0, 0);
      }
  }

  // ---- phase 1: X-branch (hi/lo) with Wr planes ----
#pragma unroll
  for (int s = 0; s < 4; ++s) {
    int kg = s * 4 + lg;
    int k0 = kg * 8;
    bf16x8 bh[4], bl[4];
#pragma unroll
    for (int nf = 0; nf < 4; ++nf) {
      const ushort* bp = Wp + 32768 + (((n0 >> 4) + nf) << 11) + (kg * 16 + li) * 8;
      bh[nf] = *(const bf16x8*)bp;
      bl[nf] = *(const bf16x8*)(bp + 16384);
    }
    bf16x8 ah[2], al[2];
#pragma unroll
    for (int mf = 0; mf < 2; ++mf) {
      ah[mf] = *(const bf16x8*)(Xh + (size_t)rows[mf] * 128 + k0);
      al[mf] = *(const bf16x8*)(Xl + (size_t)rows[mf] * 128 + k0);
    }
#pragma unroll
    for (int mf = 0; mf < 2; ++mf)
#pragma unroll
      for (int nf = 0; nf < 4; ++nf) {
        acc[mf][nf] = __builtin_amdgcn_mfma_f32_16x16x32_bf16(ah[mf], bh[nf], acc[mf][nf], 0, 0, 0);
        acc[mf][nf] = __builtin_amdgcn_mfma_f32_16x16x32_bf16(ah[mf], bl[nf], acc[mf][nf], 0, 0, 0);
        acc[mf][nf] = __builtin_amdgcn_mfma_f32_16x16x32_bf16(al[mf], bh[nf], acc[mf][nf], 0, 0, 0);
      }
  }

#pragma unroll
  for (int nf = 0; nf < 4; ++nf) {
    int colj = n0 + nf * 16 + li;
    float bj = bias[colj];
#pragma unroll
    for (int mf = 0; mf < 2; ++mf) {
#pragma unroll
      for (int r = 0; r < 4; ++r) {
        int row = m0 + mf * 16 + lg * 4 + r;
        if (row < n) {
          float v = fmaxf(acc[mf][nf][r] + bj, 0.f);
          size_t o = (size_t)row * 128 + colj;
          if (out_f32) {
            Hf[o] = v;
          } else {
            ushort h = f2bf(v);
            Hh[o] = h;
            Hl[o] = f2bf(v - bf2f(h));
          }
        }
      }
    }
  }
}

// ================= global mean pool (boundary-based, no atomics) =================

__global__ void gbound_kernel(const int* __restrict__ batch, int* __restrict__ gstart, int n,
                              int G) {
  int i = blockIdx.x * 256 + threadIdx.x;
  if (i >= n) return;
  int b = batch[i];
  if (i == 0) {
    for (int g = 0; g <= b; ++g) gstart[g] = 0;
  } else {
    int p = batch[i - 1];
    for (int g = p + 1; g <= b; ++g) gstart[g] = i;
  }
  if (i == n - 1) {
    for (int g = b + 1; g <= G; ++g) gstart[g] = n;
  }
}

// one block per graph; 256 thr = 8 rowgroups x 32 float4-dims; LDS reduce; direct store
__global__ __launch_bounds__(256) void pool2_kernel(const float* __restrict__ H,
                                                    const int* __restrict__ gstart,
                                                    float* __restrict__ out) {
  int g = blockIdx.x;
  int t = threadIdx.x;
  int d4 = t & 31;
  int ro = t >> 5;
  int beg = gstart[g], end = gstart[g + 1];
  float4 acc = make_float4(0.f, 0.f, 0.f, 0.f);
#pragma unroll 4
  for (int r = beg + ro; r < end; r += 8) {
    float4 v = *(const float4*)(H + (size_t)r * 128 + d4 * 4);
    acc.x += v.x;
    acc.y += v.y;
    acc.z += v.z;
    acc.w += v.w;
  }
  __shared__ float4 sred[8][32];
  sred[ro][d4] = acc;
  __syncthreads();
  if (ro == 0) {
    float4 s = sred[0][d4];
#pragma unroll
    for (int r = 1; r < 8; ++r) {
      float4 v = sred[r][d4];
      s.x += v.x;
      s.y += v.y;
      s.z += v.z;
      s.w += v.w;
    }
    int cnt = end - beg;
    float inv = 1.0f / (float)(cnt > 1 ? cnt : 1);
    s.x *= inv;
    s.y *= inv;
    s.z *= inv;
    s.w *= inv;
    *(float4*)(out + (size_t)g * 128 + d4 * 4) = s;
  }
}

// ================= host =================

extern "C" void kernel_launch(void* const* d_in, const int* in_sizes, int n_in,
                              void* d_out, int out_size, void* d_ws, size_t ws_size,
                              hipStream_t stream) {
  const float* x = (const float*)d_in[0];
  const int* ei = (const int*)d_in[1];
  const int* batch = (const int*)d_in[2];
  const float* Wl0 = (const float*)d_in[3];
  const float* Wr0 = (const float*)d_in[4];
  const float* b0 = (const float*)d_in[5];
  const float* Wl1 = (const float*)d_in[6];
  const float* Wr1 = (const float*)d_in[7];
  const float* b1 = (const float*)d_in[8];
  const float* Wl2 = (const float*)d_in[9];
  const float* Wr2 = (const float*)d_in[10];
  const float* b2 = (const float*)d_in[11];
  float* out = (float*)d_out;

  const int N = in_sizes[0] / 128;
  const int E = in_sizes[1] / 2;
  const int G = out_size / 128;
  const int K = (N + 255) >> 8;
  const size_t NF = (size_t)N * 128;

  char* ws = (char*)d_ws;
  size_t off = 0;
  auto carve = [&](size_t bytes) {
    size_t o = align_up(off, 512);
    off = o + bytes;
    return (void*)(ws + o);
  };
  int* row_ptr = (int*)carve(((size_t)N + 1) * 4);
  int* bcnt = (int*)carve(1024 * 4);
  int* bbase = (int*)carve(1024 * 4);
  int* bcur = (int*)carve(1024 * 4);
  int* gstart = (int*)carve(((size_t)G + 1) * 4);
  int* col = (int*)carve((size_t)E * 4);
  ushort* P0 = (ushort*)carve(NF * 4);  // hi plane [NF], lo plane [NF]
  ushort* P1 = (ushort*)carve(NF * 4);
  ushort* M = (ushort*)carve(NF * 2);   // hi only
  ushort* Wp = (ushort*)carve(3 * 65536 * 2);
  (void)ws_size;

  ushort *P0h = P0, *P0l = P0 + NF;
  ushort *P1h = P1, *P1l = P1 + NF;
  int2* ebuf = (int2*)M;   // ebuf (12.8MB) aliases M (25.6MB); dead before first aggr
  float* Hf = (float*)P1;  // final fp32 H aliases P1 (dead after layer-1 gemm)

  // ---- bucketed CSR build ----
  hipMemsetAsync(bcnt, 0, 1024 * 4, stream);
  int cgrid_e = (E + 4095) / 4096;
  hipLaunchKernelGGL(bhist_kernel, dim3(cgrid_e), dim3(256), 0, stream, ei, bcnt, E, K);
  hipLaunchKernelGGL(bscan_kernel, dim3(1), dim3(1024), 0, stream, bcnt, bbase, bcur, K);
  hipLaunchKernelGGL(bscatter_kernel, dim3(cgrid_e), dim3(256), 0, stream, ei, bcur, ebuf, E);
  hipLaunchKernelGGL(fine_kernel, dim3(K), dim3(256), 0, stream, bbase, ebuf, row_ptr, col, E, N,
                     K);

  // ---- conversions + graph bounds ----
  int cgrid = (int)((NF / 4 + 255) / 256);
  hipLaunchKernelGGL(convx_kernel, dim3(cgrid), dim3(256), 0, stream, x, P0h, P0l, (int)(NF / 4));
  hipLaunchKernelGGL(wconv_kernel, dim3(16, 6), dim3(256), 0, stream, Wl0, Wr0, Wl1, Wr1, Wl2,
                     Wr2, Wp);
  int ngrid = (N + 255) / 256;
  hipLaunchKernelGGL(gbound_kernel, dim3(ngrid), dim3(256), 0, stream, batch, gstart, N, G);

  int agrid = (N + 3) / 4;
  int ggrid = (N + 63) / 64;

  // ---- layer 0 ----
  hipLaunchKernelGGL(aggr_kernel, dim3(agrid), dim3(256), 0, stream, P0h, row_ptr, col, M, N);
  hipLaunchKernelGGL(gemm_kernel, dim3(ggrid), dim3(256), 0, stream, M, P0h, P0l, Wp, b0, P1h,
                     P1l, (float*)nullptr, N, 0);
  // ---- layer 1 ----
  hipLaunchKernelGGL(aggr_kernel, dim3(agrid), dim3(256), 0, stream, P1h, row_ptr, col, M, N);
  hipLaunchKernelGGL(gemm_kernel, dim3(ggrid), dim3(256), 0, stream, M, P1h, P1l, Wp + 65536, b1,
                     P0h, P0l, (float*)nullptr, N, 0);
  // ---- layer 2 -> fp32 Hf ----
  hipLaunchKernelGGL(aggr_kernel, dim3(agrid), dim3(256), 0, stream, P0h, row_ptr, col, M, N);
  hipLaunchKernelGGL(gemm_kernel, dim3(ggrid), dim3(256), 0, stream, M, P0h, P0l, Wp + 2 * 65536,
                     b2, (ushort*)nullptr, (ushort*)nullptr, Hf, N, 1);

  // ---- pool ----
  hipLaunchKernelGGL(pool2_kernel, dim3(G), dim3(256), 0, stream, Hf, gstart, out);
}

// Round 8
// 368.222 us; speedup vs baseline: 3.6006x; 1.1798x over previous
//
#include <hip/hip_runtime.h>

static inline size_t align_up(size_t x, size_t a) { return (x + a - 1) & ~(a - 1); }

using bf16x8 = __attribute__((ext_vector_type(8))) short;
using f32x4 = __attribute__((ext_vector_type(4))) float;

__device__ inline ushort f2bf(float x) {  // RNE float->bf16
  unsigned u = __float_as_uint(x);
  return (ushort)((u + 0x7fffu + ((u >> 16) & 1u)) >> 16);
}
__device__ inline float bf2f(ushort h) { return __uint_as_float((unsigned)h << 16); }

// ================= bucketed CSR build =================
// buckets of 256 consecutive dst nodes; K = ceil(N/256) (<=1024)

__global__ void bhist_kernel(const int* __restrict__ ei, int* __restrict__ bcnt, int E, int K) {
  __shared__ int lh[1024];
  int t = threadIdx.x;
  for (int i = t; i < 1024; i += 256) lh[i] = 0;
  __syncthreads();
  int base = blockIdx.x * 4096;
#pragma unroll
  for (int r = 0; r < 16; ++r) {
    int e = base + r * 256 + t;
    if (e < E) atomicAdd(&lh[ei[(size_t)E + e] >> 8], 1);
  }
  __syncthreads();
  for (int i = t; i < K; i += 256)
    if (lh[i]) atomicAdd(&bcnt[i], lh[i]);
}

__global__ void bscan_kernel(const int* __restrict__ bcnt, int* __restrict__ bbase,
                             int* __restrict__ bcur, int K) {
  __shared__ int sb[1024];
  int t = threadIdx.x;  // 1024
  int v = (t < K) ? bcnt[t] : 0;
  sb[t] = v;
  __syncthreads();
  int acc = v;
  for (int d = 1; d < 1024; d <<= 1) {
    int add = (t >= d) ? sb[t - d] : 0;
    __syncthreads();
    acc += add;
    sb[t] = acc;
    __syncthreads();
  }
  if (t < K) {
    int ex = acc - v;  // exclusive
    bbase[t] = ex;
    bcur[t] = ex;
  }
}

__global__ void bscatter_kernel(const int* __restrict__ ei, int* __restrict__ bcur,
                                int2* __restrict__ ebuf, int E) {
  __shared__ int lh[1024];
  __shared__ int lbase[1024];
  int t = threadIdx.x;
  for (int i = t; i < 1024; i += 256) lh[i] = 0;
  __syncthreads();
  int base = blockIdx.x * 4096;
  int src[16], dst[16];
#pragma unroll
  for (int r = 0; r < 16; ++r) {
    int e = base + r * 256 + t;
    if (e < E) {
      src[r] = ei[e];
      dst[r] = ei[(size_t)E + e];
      atomicAdd(&lh[dst[r] >> 8], 1);
    } else {
      dst[r] = -1;
    }
  }
  __syncthreads();
  for (int i = t; i < 1024; i += 256) {
    int c = lh[i];
    lbase[i] = c ? atomicAdd(&bcur[i], c) : 0;
    lh[i] = 0;
  }
  __syncthreads();
#pragma unroll
  for (int r = 0; r < 16; ++r) {
    if (dst[r] >= 0) {
      int b = dst[r] >> 8;
      int rank = atomicAdd(&lh[b], 1);
      ebuf[lbase[b] + rank] = make_int2(src[r], dst[r]);
    }
  }
}

__global__ void fine_kernel(const int* __restrict__ bbase, const int2* __restrict__ ebuf,
                            int* __restrict__ row_ptr, int* __restrict__ col, int E, int N,
                            int K) {
  int bkt = blockIdx.x;
  int nb0 = bkt << 8;
  int t = threadIdx.x;  // 256
  int base = bbase[bkt];
  int endi = (bkt + 1 < K) ? bbase[bkt + 1] : E;
  __shared__ int sdeg[256];
  __shared__ int cur[256];
  sdeg[t] = 0;
  __syncthreads();
  for (int i = base + t; i < endi; i += 256) atomicAdd(&sdeg[ebuf[i].y & 255], 1);
  __syncthreads();
  int v = sdeg[t];
  int acc = v;
  for (int d = 1; d < 256; d <<= 1) {
    int add = (t >= d) ? sdeg[t - d] : 0;
    __syncthreads();
    acc += add;
    sdeg[t] = acc;
    __syncthreads();
  }
  int gp = base + (acc - v);  // exclusive prefix
  if (nb0 + t < N) row_ptr[nb0 + t] = gp;
  if (bkt == K - 1 && t == 0) row_ptr[N] = E;
  cur[t] = gp;
  __syncthreads();
  for (int i = base + t; i < endi; i += 256) {
    int2 sd = ebuf[i];
    int slot = atomicAdd(&cur[sd.y & 255], 1);
    col[slot] = sd.x;
  }
}

// ================= conversions =================

// x fp32 -> bf16 plane (hi only)
__global__ void convx_kernel(const float* __restrict__ x, ushort* __restrict__ Xh, int total4) {
  int i = blockIdx.x * 256 + threadIdx.x;
  if (i >= total4) return;
  float4 v = *(const float4*)(x + (size_t)i * 4);
  ushort4 h;
  h.x = f2bf(v.x);
  h.y = f2bf(v.y);
  h.z = f2bf(v.z);
  h.w = f2bf(v.w);
  *(ushort4*)(Xh + (size_t)i * 4) = h;
}

// W [128 out][128 k] fp32 -> swizzled fragment-native bf16 planes (hi, lo separate)
// dst(j,k) = (j>>4)*2048 + ((k>>3)*16 + (j&15))*8 + (k&7)
__global__ void wconv_kernel(const float* Wl0, const float* Wr0, const float* Wl1,
                             const float* Wr1, const float* Wl2, const float* Wr2,
                             ushort* __restrict__ Wp) {
  int m = blockIdx.y;  // 0..5
  const float* src = (m == 0) ? Wl0 : (m == 1) ? Wr0 : (m == 2) ? Wl1
                   : (m == 3) ? Wr1 : (m == 4) ? Wl2 : Wr2;
  int layer = m >> 1, part = m & 1;
  ushort* dh = Wp + layer * 65536 + part * 32768;
  ushort* dl = dh + 16384;
  int i = blockIdx.x * 256 + threadIdx.x;  // 0..4095
  int j = i >> 5;
  int k = (i & 31) * 4;
  float4 v = *(const float4*)(src + (size_t)j * 128 + k);
  int doff = ((j >> 4) << 11) + (((k >> 3) << 4) + (j & 15)) * 8 + (k & 7);
  ushort4 h, l;
  h.x = f2bf(v.x); l.x = f2bf(v.x - bf2f(h.x));
  h.y = f2bf(v.y); l.y = f2bf(v.y - bf2f(h.y));
  h.z = f2bf(v.z); l.z = f2bf(v.z - bf2f(h.z));
  h.w = f2bf(v.w); l.w = f2bf(v.w - bf2f(h.w));
  *(ushort4*)(dh + doff) = h;
  *(ushort4*)(dl + doff) = l;
}

// ================= mean aggregation (bf16 plane, 256B/row gather) =================

__global__ void aggr_kernel(const ushort* __restrict__ Xh, const int* __restrict__ row_ptr,
                            const int* __restrict__ col, ushort* __restrict__ Mh, int n) {
  int node = blockIdx.x * 4 + (threadIdx.x >> 6);
  if (node >= n) return;
  int lane = threadIdx.x & 63;
  int k0 = lane * 2;
  int beg = row_ptr[node], end = row_ptr[node + 1];
  float s0 = 0.f, s1 = 0.f, t0 = 0.f, t1 = 0.f;
  int e = beg;
  for (; e + 4 <= end; e += 4) {
    int c0 = col[e], c1 = col[e + 1], c2 = col[e + 2], c3 = col[e + 3];
    ushort2 u0 = *(const ushort2*)(Xh + (size_t)c0 * 128 + k0);
    ushort2 u1 = *(const ushort2*)(Xh + (size_t)c1 * 128 + k0);
    ushort2 u2 = *(const ushort2*)(Xh + (size_t)c2 * 128 + k0);
    ushort2 u3 = *(const ushort2*)(Xh + (size_t)c3 * 128 + k0);
    s0 += bf2f(u0.x) + bf2f(u1.x);
    s1 += bf2f(u0.y) + bf2f(u1.y);
    t0 += bf2f(u2.x) + bf2f(u3.x);
    t1 += bf2f(u2.y) + bf2f(u3.y);
  }
  for (; e < end; ++e) {
    int c = col[e];
    ushort2 u = *(const ushort2*)(Xh + (size_t)c * 128 + k0);
    s0 += bf2f(u.x);
    s1 += bf2f(u.y);
  }
  s0 += t0;
  s1 += t1;
  int d = end - beg;
  float inv = 1.0f / (float)(d > 1 ? d : 1);
  ushort2 o;
  o.x = f2bf(s0 * inv);
  o.y = f2bf(s1 * inv);
  *(ushort2*)(Mh + (size_t)node * 128 + k0) = o;
}

// ================= LDS-staged split-W MFMA GEMM =================
// H = relu(M @ Wl^T + X @ Wr^T + b); A bf16 (LDS-staged, XOR-swizzled);
// W split hi/lo swizzled fragment-native (L2-resident); 2 MFMA/product.
// Block: 4 waves = 64 rows x 128 cols; epilogue via LDS for dense stores.

__global__ __launch_bounds__(256) void gemm_kernel(
    const ushort* __restrict__ Mh, const ushort* __restrict__ Xh,
    const ushort* __restrict__ Wp, const float* __restrict__ bias,
    ushort* __restrict__ Hh, float* __restrict__ Hf, int n, int out_f32) {
  __shared__ char smem[32768];
  ushort* sM = (ushort*)smem;  // [64][128] swizzled content
  ushort* sX = sM + 8192;      // [64][128]
  int t = threadIdx.x;
  int lane = t & 63;
  int li = lane & 15, lg = lane >> 4;
  int w = t >> 6;
  int m0g = blockIdx.x * 64;
  int mw = (w >> 1) * 32;  // wave row offset (block-local)
  int n0 = (w & 1) * 64;

  // ---- stage M,X tiles: linear LDS dest + inverse-swizzled global source ----
  {
    int rowb = t >> 4, g = t & 15;
#pragma unroll
    for (int it = 0; it < 4; ++it) {
      int r = it * 16 + rowb;
      int srcrow = m0g + r;
      if (srcrow > n - 1) srcrow = n - 1;
      int sb = (g * 16) ^ ((r & 7) << 4);
      const char* gm = (const char*)Mh + (size_t)srcrow * 256 + sb;
      const char* gx = (const char*)Xh + (size_t)srcrow * 256 + sb;
      __builtin_amdgcn_global_load_lds(
          (const __attribute__((address_space(1))) void*)gm,
          (__attribute__((address_space(3))) void*)(sM + r * 128 + g * 8), 16, 0, 0);
      __builtin_amdgcn_global_load_lds(
          (const __attribute__((address_space(1))) void*)gx,
          (__attribute__((address_space(3))) void*)(sX + r * 128 + g * 8), 16, 0, 0);
    }
  }
  __syncthreads();

  f32x4 acc[2][4] = {};

#pragma unroll
  for (int ph = 0; ph < 2; ++ph) {
    const ushort* sA = ph ? sX : sM;
    const ushort* Wb = Wp + ph * 32768;
#pragma unroll
    for (int s = 0; s < 4; ++s) {
      int kg = s * 4 + lg;
      bf16x8 bh[4], bl[4];
#pragma unroll
      for (int nf = 0; nf < 4; ++nf) {
        const ushort* bp = Wb + (((n0 >> 4) + nf) << 11) + (kg * 16 + li) * 8;
        bh[nf] = *(const bf16x8*)bp;
        bl[nf] = *(const bf16x8*)(bp + 16384);
      }
      bf16x8 a[2];
#pragma unroll
      for (int mf = 0; mf < 2; ++mf) {
        int r = mw + mf * 16 + li;
        int kb = (kg * 16) ^ ((r & 7) << 4);  // swizzled read
        a[mf] = *(const bf16x8*)(sA + r * 128 + (kb >> 1));
      }
#pragma unroll
      for (int mf = 0; mf < 2; ++mf)
#pragma unroll
        for (int nf = 0; nf < 4; ++nf) {
          acc[mf][nf] =
              __builtin_amdgcn_mfma_f32_16x16x32_bf16(a[mf], bh[nf], acc[mf][nf], 0, 0, 0);
          acc[mf][nf] =
              __builtin_amdgcn_mfma_f32_16x16x32_bf16(a[mf], bl[nf], acc[mf][nf], 0, 0, 0);
        }
    }
  }

  __syncthreads();  // A-tile reads done; reuse smem for output staging

  if (!out_f32) {
    ushort* sO = (ushort*)smem;  // [64][128]
#pragma unroll
    for (int nf = 0; nf < 4; ++nf) {
      int c = n0 + nf * 16 + li;
      float bj = bias[c];
#pragma unroll
      for (int mf = 0; mf < 2; ++mf)
#pragma unroll
        for (int r = 0; r < 4; ++r) {
          int rl = mw + mf * 16 + lg * 4 + r;
          sO[rl * 128 + c] = f2bf(fmaxf(acc[mf][nf][r] + bj, 0.f));
        }
    }
    __syncthreads();
    int rowb = t >> 4, g = t & 15;
#pragma unroll
    for (int it = 0; it < 4; ++it) {
      int r = it * 16 + rowb;
      if (m0g + r < n)
        *(uint4*)(Hh + (size_t)(m0g + r) * 128 + g * 8) = *(const uint4*)(sO + r * 128 + g * 8);
    }
  } else {
    float* sF = (float*)smem;  // [64][128] fp32 = 32KB
#pragma unroll
    for (int nf = 0; nf < 4; ++nf) {
      int c = n0 + nf * 16 + li;
      float bj = bias[c];
#pragma unroll
      for (int mf = 0; mf < 2; ++mf)
#pragma unroll
        for (int r = 0; r < 4; ++r) {
          int rl = mw + mf * 16 + lg * 4 + r;
          sF[rl * 128 + c] = fmaxf(acc[mf][nf][r] + bj, 0.f);
        }
    }
    __syncthreads();
    int rowb = t >> 5, g = t & 31;
#pragma unroll
    for (int it = 0; it < 8; ++it) {
      int r = it * 8 + rowb;
      if (m0g + r < n)
        *(float4*)(Hf + (size_t)(m0g + r) * 128 + g * 4) = *(const float4*)(sF + r * 128 + g * 4);
    }
  }
}

// ================= global mean pool (boundary-based, no atomics) =================

__global__ void gbound_kernel(const int* __restrict__ batch, int* __restrict__ gstart, int n,
                              int G) {
  int i = blockIdx.x * 256 + threadIdx.x;
  if (i >= n) return;
  int b = batch[i];
  if (i == 0) {
    for (int g = 0; g <= b; ++g) gstart[g] = 0;
  } else {
    int p = batch[i - 1];
    for (int g = p + 1; g <= b; ++g) gstart[g] = i;
  }
  if (i == n - 1) {
    for (int g = b + 1; g <= G; ++g) gstart[g] = n;
  }
}

__global__ __launch_bounds__(256) void pool2_kernel(const float* __restrict__ H,
                                                    const int* __restrict__ gstart,
                                                    float* __restrict__ out) {
  int g = blockIdx.x;
  int t = threadIdx.x;
  int d4 = t & 31;
  int ro = t >> 5;
  int beg = gstart[g], end = gstart[g + 1];
  float4 acc = make_float4(0.f, 0.f, 0.f, 0.f);
#pragma unroll 4
  for (int r = beg + ro; r < end; r += 8) {
    float4 v = *(const float4*)(H + (size_t)r * 128 + d4 * 4);
    acc.x += v.x;
    acc.y += v.y;
    acc.z += v.z;
    acc.w += v.w;
  }
  __shared__ float4 sred[8][32];
  sred[ro][d4] = acc;
  __syncthreads();
  if (ro == 0) {
    float4 s = sred[0][d4];
#pragma unroll
    for (int r = 1; r < 8; ++r) {
      float4 v = sred[r][d4];
      s.x += v.x;
      s.y += v.y;
      s.z += v.z;
      s.w += v.w;
    }
    int cnt = end - beg;
    float inv = 1.0f / (float)(cnt > 1 ? cnt : 1);
    s.x *= inv;
    s.y *= inv;
    s.z *= inv;
    s.w *= inv;
    *(float4*)(out + (size_t)g * 128 + d4 * 4) = s;
  }
}

// ================= host =================

extern "C" void kernel_launch(void* const* d_in, const int* in_sizes, int n_in,
                              void* d_out, int out_size, void* d_ws, size_t ws_size,
                              hipStream_t stream) {
  const float* x = (const float*)d_in[0];
  const int* ei = (const int*)d_in[1];
  const int* batch = (const int*)d_in[2];
  const float* Wl0 = (const float*)d_in[3];
  const float* Wr0 = (const float*)d_in[4];
  const float* b0 = (const float*)d_in[5];
  const float* Wl1 = (const float*)d_in[6];
  const float* Wr1 = (const float*)d_in[7];
  const float* b1 = (const float*)d_in[8];
  const float* Wl2 = (const float*)d_in[9];
  const float* Wr2 = (const float*)d_in[10];
  const float* b2 = (const float*)d_in[11];
  float* out = (float*)d_out;

  const int N = in_sizes[0] / 128;
  const int E = in_sizes[1] / 2;
  const int G = out_size / 128;
  const int K = (N + 255) >> 8;
  const size_t NF = (size_t)N * 128;

  char* ws = (char*)d_ws;
  size_t off = 0;
  auto carve = [&](size_t bytes) {
    size_t o = align_up(off, 512);
    off = o + bytes;
    return (void*)(ws + o);
  };
  int* row_ptr = (int*)carve(((size_t)N + 1) * 4);
  int* bcnt = (int*)carve(1024 * 4);
  int* bbase = (int*)carve(1024 * 4);
  int* bcur = (int*)carve(1024 * 4);
  int* gstart = (int*)carve(((size_t)G + 1) * 4);
  int* col = (int*)carve((size_t)E * 4);
  ushort* P0 = (ushort*)carve(NF * 2);  // bf16 feature planes
  ushort* P1 = (ushort*)carve(NF * 2);
  ushort* M = (ushort*)carve(NF * 2);
  float* Hf = (float*)carve(NF * 4);  // final fp32 features
  ushort* Wp = (ushort*)carve(3 * 65536 * 2);
  (void)ws_size;

  int2* ebuf = (int2*)Hf;  // ebuf (12.8MB) aliases Hf (51.2MB); dead before layer2 gemm

  // ---- bucketed CSR build ----
  hipMemsetAsync(bcnt, 0, 1024 * 4, stream);
  int cgrid_e = (E + 4095) / 4096;
  hipLaunchKernelGGL(bhist_kernel, dim3(cgrid_e), dim3(256), 0, stream, ei, bcnt, E, K);
  hipLaunchKernelGGL(bscan_kernel, dim3(1), dim3(1024), 0, stream, bcnt, bbase, bcur, K);
  hipLaunchKernelGGL(bscatter_kernel, dim3(cgrid_e), dim3(256), 0, stream, ei, bcur, ebuf, E);
  hipLaunchKernelGGL(fine_kernel, dim3(K), dim3(256), 0, stream, bbase, ebuf, row_ptr, col, E, N,
                     K);

  // ---- conversions + graph bounds ----
  int cgrid = (int)((NF / 4 + 255) / 256);
  hipLaunchKernelGGL(convx_kernel, dim3(cgrid), dim3(256), 0, stream, x, P0, (int)(NF / 4));
  hipLaunchKernelGGL(wconv_kernel, dim3(16, 6), dim3(256), 0, stream, Wl0, Wr0, Wl1, Wr1, Wl2,
                     Wr2, Wp);
  int ngrid = (N + 255) / 256;
  hipLaunchKernelGGL(gbound_kernel, dim3(ngrid), dim3(256), 0, stream, batch, gstart, N, G);

  int agrid = (N + 3) / 4;
  int ggrid = (N + 63) / 64;

  // ---- layer 0 ----
  hipLaunchKernelGGL(aggr_kernel, dim3(agrid), dim3(256), 0, stream, P0, row_ptr, col, M, N);
  hipLaunchKernelGGL(gemm_kernel, dim3(ggrid), dim3(256), 0, stream, M, P0, Wp, b0, P1,
                     (float*)nullptr, N, 0);
  // ---- layer 1 ----
  hipLaunchKernelGGL(aggr_kernel, dim3(agrid), dim3(256), 0, stream, P1, row_ptr, col, M, N);
  hipLaunchKernelGGL(gemm_kernel, dim3(ggrid), dim3(256), 0, stream, M, P1, Wp + 65536, b1, P0,
                     (float*)nullptr, N, 0);
  // ---- layer 2 -> fp32 Hf ----
  hipLaunchKernelGGL(aggr_kernel, dim3(agrid), dim3(256), 0, stream, P0, row_ptr, col, M, N);
  hipLaunchKernelGGL(gemm_kernel, dim3(ggrid), dim3(256), 0, stream, M, P0, Wp + 2 * 65536, b2,
                     (ushort*)nullptr, Hf, N, 1);

  // ---- pool ----
  hipLaunchKernelGGL(pool2_kernel, dim3(G), dim3(256), 0, stream, Hf, gstart, out);
}

// Round 9
// 335.946 us; speedup vs baseline: 3.9465x; 1.0961x over previous
//
#include <hip/hip_runtime.h>

static inline size_t align_up(size_t x, size_t a) { return (x + a - 1) & ~(a - 1); }

using bf16x8 = __attribute__((ext_vector_type(8))) short;
using f32x4 = __attribute__((ext_vector_type(4))) float;

__device__ inline ushort f2bf(float x) {  // RNE float->bf16
  unsigned u = __float_as_uint(x);
  return (ushort)((u + 0x7fffu + ((u >> 16) & 1u)) >> 16);
}
__device__ inline float bf2f(ushort h) { return __uint_as_float((unsigned)h << 16); }

// ================= bucketed CSR build =================
// buckets of 256 consecutive dst nodes; K = ceil(N/256) (<=1024)

__global__ void bhist_kernel(const int* __restrict__ ei, int* __restrict__ bcnt, int E, int K) {
  __shared__ int lh[1024];
  int t = threadIdx.x;
  for (int i = t; i < 1024; i += 256) lh[i] = 0;
  __syncthreads();
  int base = blockIdx.x * 4096;
#pragma unroll
  for (int r = 0; r < 16; ++r) {
    int e = base + r * 256 + t;
    if (e < E) atomicAdd(&lh[ei[(size_t)E + e] >> 8], 1);
  }
  __syncthreads();
  for (int i = t; i < K; i += 256)
    if (lh[i]) atomicAdd(&bcnt[i], lh[i]);
}

__global__ void bscan_kernel(const int* __restrict__ bcnt, int* __restrict__ bbase,
                             int* __restrict__ bcur, int K) {
  __shared__ int sb[1024];
  int t = threadIdx.x;  // 1024
  int v = (t < K) ? bcnt[t] : 0;
  sb[t] = v;
  __syncthreads();
  int acc = v;
  for (int d = 1; d < 1024; d <<= 1) {
    int add = (t >= d) ? sb[t - d] : 0;
    __syncthreads();
    acc += add;
    sb[t] = acc;
    __syncthreads();
  }
  if (t < K) {
    int ex = acc - v;  // exclusive
    bbase[t] = ex;
    bcur[t] = ex;
  }
}

__global__ void bscatter_kernel(const int* __restrict__ ei, int* __restrict__ bcur,
                                int2* __restrict__ ebuf, int E) {
  __shared__ int lh[1024];
  __shared__ int lbase[1024];
  int t = threadIdx.x;
  for (int i = t; i < 1024; i += 256) lh[i] = 0;
  __syncthreads();
  int base = blockIdx.x * 4096;
  int src[16], dst[16];
#pragma unroll
  for (int r = 0; r < 16; ++r) {
    int e = base + r * 256 + t;
    if (e < E) {
      src[r] = ei[e];
      dst[r] = ei[(size_t)E + e];
      atomicAdd(&lh[dst[r] >> 8], 1);
    } else {
      dst[r] = -1;
    }
  }
  __syncthreads();
  for (int i = t; i < 1024; i += 256) {
    int c = lh[i];
    lbase[i] = c ? atomicAdd(&bcur[i], c) : 0;
    lh[i] = 0;
  }
  __syncthreads();
#pragma unroll
  for (int r = 0; r < 16; ++r) {
    if (dst[r] >= 0) {
      int b = dst[r] >> 8;
      int rank = atomicAdd(&lh[b], 1);
      ebuf[lbase[b] + rank] = make_int2(src[r], dst[r]);
    }
  }
}

__global__ void fine_kernel(const int* __restrict__ bbase, const int2* __restrict__ ebuf,
                            int* __restrict__ row_ptr, int* __restrict__ col, int E, int N,
                            int K) {
  int bkt = blockIdx.x;
  int nb0 = bkt << 8;
  int t = threadIdx.x;  // 256
  int base = bbase[bkt];
  int endi = (bkt + 1 < K) ? bbase[bkt + 1] : E;
  __shared__ int sdeg[256];
  __shared__ int cur[256];
  sdeg[t] = 0;
  __syncthreads();
  for (int i = base + t; i < endi; i += 256) atomicAdd(&sdeg[ebuf[i].y & 255], 1);
  __syncthreads();
  int v = sdeg[t];
  int acc = v;
  for (int d = 1; d < 256; d <<= 1) {
    int add = (t >= d) ? sdeg[t - d] : 0;
    __syncthreads();
    acc += add;
    sdeg[t] = acc;
    __syncthreads();
  }
  int gp = base + (acc - v);  // exclusive prefix
  if (nb0 + t < N) row_ptr[nb0 + t] = gp;
  if (bkt == K - 1 && t == 0) row_ptr[N] = E;
  cur[t] = gp;
  __syncthreads();
  for (int i = base + t; i < endi; i += 256) {
    int2 sd = ebuf[i];
    int slot = atomicAdd(&cur[sd.y & 255], 1);
    col[slot] = sd.x;
  }
}

// ================= conversions =================

// x fp32 -> bf16 plane
__global__ void convx_kernel(const float* __restrict__ x, ushort* __restrict__ Xh, int total4) {
  int i = blockIdx.x * 256 + threadIdx.x;
  if (i >= total4) return;
  float4 v = *(const float4*)(x + (size_t)i * 4);
  ushort4 h;
  h.x = f2bf(v.x);
  h.y = f2bf(v.y);
  h.z = f2bf(v.z);
  h.w = f2bf(v.w);
  *(ushort4*)(Xh + (size_t)i * 4) = h;
}

// W [128 out][128 k] fp32 -> swizzled fragment-native bf16 planes (hi, lo separate)
// dst(j,k) = (j>>4)*2048 + ((k>>3)*16 + (j&15))*8 + (k&7)
__global__ void wconv_kernel(const float* Wl0, const float* Wr0, const float* Wl1,
                             const float* Wr1, const float* Wl2, const float* Wr2,
                             ushort* __restrict__ Wp) {
  int m = blockIdx.y;  // 0..5
  const float* src = (m == 0) ? Wl0 : (m == 1) ? Wr0 : (m == 2) ? Wl1
                   : (m == 3) ? Wr1 : (m == 4) ? Wl2 : Wr2;
  int layer = m >> 1, part = m & 1;
  ushort* dh = Wp + layer * 65536 + part * 32768;
  ushort* dl = dh + 16384;
  int i = blockIdx.x * 256 + threadIdx.x;  // 0..4095
  int j = i >> 5;
  int k = (i & 31) * 4;
  float4 v = *(const float4*)(src + (size_t)j * 128 + k);
  int doff = ((j >> 4) << 11) + (((k >> 3) << 4) + (j & 15)) * 8 + (k & 7);
  ushort4 h, l;
  h.x = f2bf(v.x); l.x = f2bf(v.x - bf2f(h.x));
  h.y = f2bf(v.y); l.y = f2bf(v.y - bf2f(h.y));
  h.z = f2bf(v.z); l.z = f2bf(v.z - bf2f(h.z));
  h.w = f2bf(v.w); l.w = f2bf(v.w - bf2f(h.w));
  *(ushort4*)(dh + doff) = h;
  *(ushort4*)(dl + doff) = l;
}

// ================= mean aggregation (bf16x8/lane, 4 edges/wave) =================
// lane = (eg: edge group 0..3) x (dim octet 0..15); 16 lanes x 16B = one 256B row;
// wave processes 4 edges in parallel, 2-deep unrolled => 8 edges in flight.

__global__ void aggr_kernel(const ushort* __restrict__ Xh, const int* __restrict__ row_ptr,
                            const int* __restrict__ col, ushort* __restrict__ Mh, int n) {
  int node = blockIdx.x * 4 + (threadIdx.x >> 6);
  if (node >= n) return;
  int lane = threadIdx.x & 63;
  int eg = lane >> 4;        // edge group 0..3
  int d0 = (lane & 15) * 8;  // dim octet
  int beg = row_ptr[node], end = row_ptr[node + 1];
  float s[8] = {};
  int e = beg + eg;
  for (; e + 4 < end; e += 8) {
    int c0 = col[e];
    int c1 = col[e + 4];
    bf16x8 u0 = *(const bf16x8*)(Xh + (size_t)c0 * 128 + d0);
    bf16x8 u1 = *(const bf16x8*)(Xh + (size_t)c1 * 128 + d0);
#pragma unroll
    for (int k = 0; k < 8; ++k) s[k] += bf2f((ushort)u0[k]) + bf2f((ushort)u1[k]);
  }
  if (e < end) {
    int c = col[e];
    bf16x8 u = *(const bf16x8*)(Xh + (size_t)c * 128 + d0);
#pragma unroll
    for (int k = 0; k < 8; ++k) s[k] += bf2f((ushort)u[k]);
  }
  // combine the 4 edge groups (all lanes participate)
#pragma unroll
  for (int k = 0; k < 8; ++k) {
    s[k] += __shfl_xor(s[k], 16, 64);
    s[k] += __shfl_xor(s[k], 32, 64);
  }
  if (eg == 0) {
    int d = end - beg;
    float inv = 1.0f / (float)(d > 1 ? d : 1);
    bf16x8 o;
#pragma unroll
    for (int k = 0; k < 8; ++k) o[k] = (short)f2bf(s[k] * inv);
    *(bf16x8*)(Mh + (size_t)node * 128 + d0) = o;
  }
}

// ================= LDS-staged split-W MFMA GEMM =================
// H = relu(M @ Wl^T + X @ Wr^T + b); A bf16 (LDS-staged, XOR-swizzled);
// W split hi/lo swizzled fragment-native (L2-resident); 2 MFMA/product.
// Block: 4 waves = 64 rows x 128 cols; epilogue via LDS for dense stores.

__global__ __launch_bounds__(256) void gemm_kernel(
    const ushort* __restrict__ Mh, const ushort* __restrict__ Xh,
    const ushort* __restrict__ Wp, const float* __restrict__ bias,
    ushort* __restrict__ Hh, float* __restrict__ Hf, int n, int out_f32) {
  __shared__ char smem[32768];
  ushort* sM = (ushort*)smem;  // [64][128] swizzled content
  ushort* sX = sM + 8192;      // [64][128]
  int t = threadIdx.x;
  int lane = t & 63;
  int li = lane & 15, lg = lane >> 4;
  int w = t >> 6;
  int m0g = blockIdx.x * 64;
  int mw = (w >> 1) * 32;  // wave row offset (block-local)
  int n0 = (w & 1) * 64;

  // ---- stage M,X tiles: linear LDS dest + inverse-swizzled global source ----
  {
    int rowb = t >> 4, g = t & 15;
#pragma unroll
    for (int it = 0; it < 4; ++it) {
      int r = it * 16 + rowb;
      int srcrow = m0g + r;
      if (srcrow > n - 1) srcrow = n - 1;
      int sb = (g * 16) ^ ((r & 7) << 4);
      const char* gm = (const char*)Mh + (size_t)srcrow * 256 + sb;
      const char* gx = (const char*)Xh + (size_t)srcrow * 256 + sb;
      __builtin_amdgcn_global_load_lds(
          (const __attribute__((address_space(1))) void*)gm,
          (__attribute__((address_space(3))) void*)(sM + r * 128 + g * 8), 16, 0, 0);
      __builtin_amdgcn_global_load_lds(
          (const __attribute__((address_space(1))) void*)gx,
          (__attribute__((address_space(3))) void*)(sX + r * 128 + g * 8), 16, 0, 0);
    }
  }
  __syncthreads();

  f32x4 acc[2][4] = {};

#pragma unroll
  for (int ph = 0; ph < 2; ++ph) {
    const ushort* sA = ph ? sX : sM;
    const ushort* Wb = Wp + ph * 32768;
#pragma unroll
    for (int s = 0; s < 4; ++s) {
      int kg = s * 4 + lg;
      bf16x8 bh[4], bl[4];
#pragma unroll
      for (int nf = 0; nf < 4; ++nf) {
        const ushort* bp = Wb + (((n0 >> 4) + nf) << 11) + (kg * 16 + li) * 8;
        bh[nf] = *(const bf16x8*)bp;
        bl[nf] = *(const bf16x8*)(bp + 16384);
      }
      bf16x8 a[2];
#pragma unroll
      for (int mf = 0; mf < 2; ++mf) {
        int r = mw + mf * 16 + li;
        int kb = (kg * 16) ^ ((r & 7) << 4);  // swizzled read
        a[mf] = *(const bf16x8*)(sA + r * 128 + (kb >> 1));
      }
#pragma unroll
      for (int mf = 0; mf < 2; ++mf)
#pragma unroll
        for (int nf = 0; nf < 4; ++nf) {
          acc[mf][nf] =
              __builtin_amdgcn_mfma_f32_16x16x32_bf16(a[mf], bh[nf], acc[mf][nf], 0, 0, 0);
          acc[mf][nf] =
              __builtin_amdgcn_mfma_f32_16x16x32_bf16(a[mf], bl[nf], acc[mf][nf], 0, 0, 0);
        }
    }
  }

  __syncthreads();  // A-tile reads done; reuse smem for output staging

  if (!out_f32) {
    ushort* sO = (ushort*)smem;  // [64][128]
#pragma unroll
    for (int nf = 0; nf < 4; ++nf) {
      int c = n0 + nf * 16 + li;
      float bj = bias[c];
#pragma unroll
      for (int mf = 0; mf < 2; ++mf)
#pragma unroll
        for (int r = 0; r < 4; ++r) {
          int rl = mw + mf * 16 + lg * 4 + r;
          sO[rl * 128 + c] = f2bf(fmaxf(acc[mf][nf][r] + bj, 0.f));
        }
    }
    __syncthreads();
    int rowb = t >> 4, g = t & 15;
#pragma unroll
    for (int it = 0; it < 4; ++it) {
      int r = it * 16 + rowb;
      if (m0g + r < n)
        *(uint4*)(Hh + (size_t)(m0g + r) * 128 + g * 8) = *(const uint4*)(sO + r * 128 + g * 8);
    }
  } else {
    float* sF = (float*)smem;  // [64][128] fp32 = 32KB
#pragma unroll
    for (int nf = 0; nf < 4; ++nf) {
      int c = n0 + nf * 16 + li;
      float bj = bias[c];
#pragma unroll
      for (int mf = 0; mf < 2; ++mf)
#pragma unroll
        for (int r = 0; r < 4; ++r) {
          int rl = mw + mf * 16 + lg * 4 + r;
          sF[rl * 128 + c] = fmaxf(acc[mf][nf][r] + bj, 0.f);
        }
    }
    __syncthreads();
    int rowb = t >> 5, g = t & 31;
#pragma unroll
    for (int it = 0; it < 8; ++it) {
      int r = it * 8 + rowb;
      if (m0g + r < n)
        *(float4*)(Hf + (size_t)(m0g + r) * 128 + g * 4) = *(const float4*)(sF + r * 128 + g * 4);
    }
  }
}

// ================= global mean pool (boundary-based, no atomics) =================

__global__ void gbound_kernel(const int* __restrict__ batch, int* __restrict__ gstart, int n,
                              int G) {
  int i = blockIdx.x * 256 + threadIdx.x;
  if (i >= n) return;
  int b = batch[i];
  if (i == 0) {
    for (int g = 0; g <= b; ++g) gstart[g] = 0;
  } else {
    int p = batch[i - 1];
    for (int g = p + 1; g <= b; ++g) gstart[g] = i;
  }
  if (i == n - 1) {
    for (int g = b + 1; g <= G; ++g) gstart[g] = n;
  }
}

__global__ __launch_bounds__(256) void pool2_kernel(const float* __restrict__ H,
                                                    const int* __restrict__ gstart,
                                                    float* __restrict__ out) {
  int g = blockIdx.x;
  int t = threadIdx.x;
  int d4 = t & 31;
  int ro = t >> 5;
  int beg = gstart[g], end = gstart[g + 1];
  float4 acc = make_float4(0.f, 0.f, 0.f, 0.f);
#pragma unroll 4
  for (int r = beg + ro; r < end; r += 8) {
    float4 v = *(const float4*)(H + (size_t)r * 128 + d4 * 4);
    acc.x += v.x;
    acc.y += v.y;
    acc.z += v.z;
    acc.w += v.w;
  }
  __shared__ float4 sred[8][32];
  sred[ro][d4] = acc;
  __syncthreads();
  if (ro == 0) {
    float4 s = sred[0][d4];
#pragma unroll
    for (int r = 1; r < 8; ++r) {
      float4 v = sred[r][d4];
      s.x += v.x;
      s.y += v.y;
      s.z += v.z;
      s.w += v.w;
    }
    int cnt = end - beg;
    float inv = 1.0f / (float)(cnt > 1 ? cnt : 1);
    s.x *= inv;
    s.y *= inv;
    s.z *= inv;
    s.w *= inv;
    *(float4*)(out + (size_t)g * 128 + d4 * 4) = s;
  }
}

// ================= host =================

extern "C" void kernel_launch(void* const* d_in, const int* in_sizes, int n_in,
                              void* d_out, int out_size, void* d_ws, size_t ws_size,
                              hipStream_t stream) {
  const float* x = (const float*)d_in[0];
  const int* ei = (const int*)d_in[1];
  const int* batch = (const int*)d_in[2];
  const float* Wl0 = (const float*)d_in[3];
  const float* Wr0 = (const float*)d_in[4];
  const float* b0 = (const float*)d_in[5];
  const float* Wl1 = (const float*)d_in[6];
  const float* Wr1 = (const float*)d_in[7];
  const float* b1 = (const float*)d_in[8];
  const float* Wl2 = (const float*)d_in[9];
  const float* Wr2 = (const float*)d_in[10];
  const float* b2 = (const float*)d_in[11];
  float* out = (float*)d_out;

  const int N = in_sizes[0] / 128;
  const int E = in_sizes[1] / 2;
  const int G = out_size / 128;
  const int K = (N + 255) >> 8;
  const size_t NF = (size_t)N * 128;

  char* ws = (char*)d_ws;
  size_t off = 0;
  auto carve = [&](size_t bytes) {
    size_t o = align_up(off, 512);
    off = o + bytes;
    return (void*)(ws + o);
  };
  int* row_ptr = (int*)carve(((size_t)N + 1) * 4);
  int* bcnt = (int*)carve(1024 * 4);
  int* bbase = (int*)carve(1024 * 4);
  int* bcur = (int*)carve(1024 * 4);
  int* gstart = (int*)carve(((size_t)G + 1) * 4);
  int* col = (int*)carve((size_t)E * 4);
  ushort* P0 = (ushort*)carve(NF * 2);  // bf16 feature planes
  ushort* P1 = (ushort*)carve(NF * 2);
  ushort* M = (ushort*)carve(NF * 2);
  float* Hf = (float*)carve(NF * 4);  // final fp32 features
  ushort* Wp = (ushort*)carve(3 * 65536 * 2);
  (void)ws_size;

  int2* ebuf = (int2*)Hf;  // ebuf (12.8MB) aliases Hf (51.2MB); dead before layer2 gemm

  // ---- bucketed CSR build ----
  hipMemsetAsync(bcnt, 0, 1024 * 4, stream);
  int cgrid_e = (E + 4095) / 4096;
  hipLaunchKernelGGL(bhist_kernel, dim3(cgrid_e), dim3(256), 0, stream, ei, bcnt, E, K);
  hipLaunchKernelGGL(bscan_kernel, dim3(1), dim3(1024), 0, stream, bcnt, bbase, bcur, K);
  hipLaunchKernelGGL(bscatter_kernel, dim3(cgrid_e), dim3(256), 0, stream, ei, bcur, ebuf, E);
  hipLaunchKernelGGL(fine_kernel, dim3(K), dim3(256), 0, stream, bbase, ebuf, row_ptr, col, E, N,
                     K);

  // ---- conversions + graph bounds ----
  int cgrid = (int)((NF / 4 + 255) / 256);
  hipLaunchKernelGGL(convx_kernel, dim3(cgrid), dim3(256), 0, stream, x, P0, (int)(NF / 4));
  hipLaunchKernelGGL(wconv_kernel, dim3(16, 6), dim3(256), 0, stream, Wl0, Wr0, Wl1, Wr1, Wl2,
                     Wr2, Wp);
  int ngrid = (N + 255) / 256;
  hipLaunchKernelGGL(gbound_kernel, dim3(ngrid), dim3(256), 0, stream, batch, gstart, N, G);

  int agrid = (N + 3) / 4;
  int ggrid = (N + 63) / 64;

  // ---- layer 0 ----
  hipLaunchKernelGGL(aggr_kernel, dim3(agrid), dim3(256), 0, stream, P0, row_ptr, col, M, N);
  hipLaunchKernelGGL(gemm_kernel, dim3(ggrid), dim3(256), 0, stream, M, P0, Wp, b0, P1,
                     (float*)nullptr, N, 0);
  // ---- layer 1 ----
  hipLaunchKernelGGL(aggr_kernel, dim3(agrid), dim3(256), 0, stream, P1, row_ptr, col, M, N);
  hipLaunchKernelGGL(gemm_kernel, dim3(ggrid), dim3(256), 0, stream, M, P1, Wp + 65536, b1, P0,
                     (float*)nullptr, N, 0);
  // ---- layer 2 -> fp32 Hf ----
  hipLaunchKernelGGL(aggr_kernel, dim3(agrid), dim3(256), 0, stream, P0, row_ptr, col, M, N);
  hipLaunchKernelGGL(gemm_kernel, dim3(ggrid), dim3(256), 0, stream, M, P0, Wp + 2 * 65536, b2,
                     (ushort*)nullptr, Hf, N, 1);

  // ---- pool ----
  hipLaunchKernelGGL(pool2_kernel, dim3(G), dim3(256), 0, stream, Hf, gstart, out);
}

// Round 10
// 333.237 us; speedup vs baseline: 3.9786x; 1.0081x over previous
//
#include <hip/hip_runtime.h>

static inline size_t align_up(size_t x, size_t a) { return (x + a - 1) & ~(a - 1); }

using bf16x8 = __attribute__((ext_vector_type(8))) short;
using f32x4 = __attribute__((ext_vector_type(4))) float;

__device__ inline ushort f2bf(float x) {  // RNE float->bf16
  unsigned u = __float_as_uint(x);
  return (ushort)((u + 0x7fffu + ((u >> 16) & 1u)) >> 16);
}
__device__ inline float bf2f(ushort h) { return __uint_as_float((unsigned)h << 16); }

// ================= bucketed CSR build =================
// buckets of 256 consecutive dst nodes; K = ceil(N/256) (<=1024)

__global__ void bhist_kernel(const int* __restrict__ ei, int* __restrict__ bcnt, int E, int K) {
  __shared__ int lh[1024];
  int t = threadIdx.x;
  for (int i = t; i < 1024; i += 256) lh[i] = 0;
  __syncthreads();
  int base = blockIdx.x * 4096;
#pragma unroll
  for (int r = 0; r < 16; ++r) {
    int e = base + r * 256 + t;
    if (e < E) atomicAdd(&lh[ei[(size_t)E + e] >> 8], 1);
  }
  __syncthreads();
  for (int i = t; i < K; i += 256)
    if (lh[i]) atomicAdd(&bcnt[i], lh[i]);
}

__global__ void bscan_kernel(const int* __restrict__ bcnt, int* __restrict__ bbase,
                             int* __restrict__ bcur, int K) {
  __shared__ int sb[1024];
  int t = threadIdx.x;  // 1024
  int v = (t < K) ? bcnt[t] : 0;
  sb[t] = v;
  __syncthreads();
  int acc = v;
  for (int d = 1; d < 1024; d <<= 1) {
    int add = (t >= d) ? sb[t - d] : 0;
    __syncthreads();
    acc += add;
    sb[t] = acc;
    __syncthreads();
  }
  if (t < K) {
    int ex = acc - v;  // exclusive
    bbase[t] = ex;
    bcur[t] = ex;
  }
}

__global__ void bscatter_kernel(const int* __restrict__ ei, int* __restrict__ bcur,
                                int2* __restrict__ ebuf, int E) {
  __shared__ int lh[1024];
  __shared__ int lbase[1024];
  int t = threadIdx.x;
  for (int i = t; i < 1024; i += 256) lh[i] = 0;
  __syncthreads();
  int base = blockIdx.x * 4096;
  int src[16], dst[16];
#pragma unroll
  for (int r = 0; r < 16; ++r) {
    int e = base + r * 256 + t;
    if (e < E) {
      src[r] = ei[e];
      dst[r] = ei[(size_t)E + e];
      atomicAdd(&lh[dst[r] >> 8], 1);
    } else {
      dst[r] = -1;
    }
  }
  __syncthreads();
  for (int i = t; i < 1024; i += 256) {
    int c = lh[i];
    lbase[i] = c ? atomicAdd(&bcur[i], c) : 0;
    lh[i] = 0;
  }
  __syncthreads();
#pragma unroll
  for (int r = 0; r < 16; ++r) {
    if (dst[r] >= 0) {
      int b = dst[r] >> 8;
      int rank = atomicAdd(&lh[b], 1);
      ebuf[lbase[b] + rank] = make_int2(src[r], dst[r]);
    }
  }
}

__global__ void fine_kernel(const int* __restrict__ bbase, const int2* __restrict__ ebuf,
                            int* __restrict__ row_ptr, int* __restrict__ col, int E, int N,
                            int K) {
  int bkt = blockIdx.x;
  int nb0 = bkt << 8;
  int t = threadIdx.x;  // 256
  int base = bbase[bkt];
  int endi = (bkt + 1 < K) ? bbase[bkt + 1] : E;
  __shared__ int sdeg[256];
  __shared__ int cur[256];
  sdeg[t] = 0;
  __syncthreads();
  for (int i = base + t; i < endi; i += 256) atomicAdd(&sdeg[ebuf[i].y & 255], 1);
  __syncthreads();
  int v = sdeg[t];
  int acc = v;
  for (int d = 1; d < 256; d <<= 1) {
    int add = (t >= d) ? sdeg[t - d] : 0;
    __syncthreads();
    acc += add;
    sdeg[t] = acc;
    __syncthreads();
  }
  int gp = base + (acc - v);  // exclusive prefix
  if (nb0 + t < N) row_ptr[nb0 + t] = gp;
  if (bkt == K - 1 && t == 0) row_ptr[N] = E;
  cur[t] = gp;
  __syncthreads();
  for (int i = base + t; i < endi; i += 256) {
    int2 sd = ebuf[i];
    int slot = atomicAdd(&cur[sd.y & 255], 1);
    col[slot] = sd.x;
  }
}

// ================= conversions =================

// x fp32 -> bf16 plane
__global__ void convx_kernel(const float* __restrict__ x, ushort* __restrict__ Xh, int total4) {
  int i = blockIdx.x * 256 + threadIdx.x;
  if (i >= total4) return;
  float4 v = *(const float4*)(x + (size_t)i * 4);
  ushort4 h;
  h.x = f2bf(v.x);
  h.y = f2bf(v.y);
  h.z = f2bf(v.z);
  h.w = f2bf(v.w);
  *(ushort4*)(Xh + (size_t)i * 4) = h;
}

// W [128 out][128 k] fp32 -> swizzled fragment-native bf16 planes (hi, lo separate)
// dst(j,k) = (j>>4)*2048 + ((k>>3)*16 + (j&15))*8 + (k&7)
__global__ void wconv_kernel(const float* Wl0, const float* Wr0, const float* Wl1,
                             const float* Wr1, const float* Wl2, const float* Wr2,
                             ushort* __restrict__ Wp) {
  int m = blockIdx.y;  // 0..5
  const float* src = (m == 0) ? Wl0 : (m == 1) ? Wr0 : (m == 2) ? Wl1
                   : (m == 3) ? Wr1 : (m == 4) ? Wl2 : Wr2;
  int layer = m >> 1, part = m & 1;
  ushort* dh = Wp + layer * 65536 + part * 32768;
  ushort* dl = dh + 16384;
  int i = blockIdx.x * 256 + threadIdx.x;  // 0..4095
  int j = i >> 5;
  int k = (i & 31) * 4;
  float4 v = *(const float4*)(src + (size_t)j * 128 + k);
  int doff = ((j >> 4) << 11) + (((k >> 3) << 4) + (j & 15)) * 8 + (k & 7);
  ushort4 h, l;
  h.x = f2bf(v.x); l.x = f2bf(v.x - bf2f(h.x));
  h.y = f2bf(v.y); l.y = f2bf(v.y - bf2f(h.y));
  h.z = f2bf(v.z); l.z = f2bf(v.z - bf2f(h.z));
  h.w = f2bf(v.w); l.w = f2bf(v.w - bf2f(h.w));
  *(ushort4*)(dh + doff) = h;
  *(ushort4*)(dl + doff) = l;
}

// ================= mean aggregation (bf16x8/lane, 4 edges/wave, 4-deep) =================
// lane = (eg: edge group 0..3) x (dim octet 0..15); 16 lanes x 16B = one 256B row;
// 4 edge groups in parallel, 4-deep unrolled => 16 rows in flight per wave.

__global__ void aggr_kernel(const ushort* __restrict__ Xh, const int* __restrict__ row_ptr,
                            const int* __restrict__ col, ushort* __restrict__ Mh, int n) {
  int node = blockIdx.x * 4 + (threadIdx.x >> 6);
  if (node >= n) return;
  int lane = threadIdx.x & 63;
  int eg = lane >> 4;        // edge group 0..3
  int d0 = (lane & 15) * 8;  // dim octet
  int beg = row_ptr[node], end = row_ptr[node + 1];
  float s[8] = {};
  int e = beg + eg;
  // 4-deep: 4 rows in flight per lane-group (16/wave)
  for (; e + 12 < end; e += 16) {
    int c0 = col[e];
    int c1 = col[e + 4];
    int c2 = col[e + 8];
    int c3 = col[e + 12];
    bf16x8 u0 = *(const bf16x8*)(Xh + (size_t)c0 * 128 + d0);
    bf16x8 u1 = *(const bf16x8*)(Xh + (size_t)c1 * 128 + d0);
    bf16x8 u2 = *(const bf16x8*)(Xh + (size_t)c2 * 128 + d0);
    bf16x8 u3 = *(const bf16x8*)(Xh + (size_t)c3 * 128 + d0);
#pragma unroll
    for (int k = 0; k < 8; ++k)
      s[k] += (bf2f((ushort)u0[k]) + bf2f((ushort)u1[k])) +
              (bf2f((ushort)u2[k]) + bf2f((ushort)u3[k]));
  }
  for (; e + 4 < end; e += 8) {
    int c0 = col[e];
    int c1 = col[e + 4];
    bf16x8 u0 = *(const bf16x8*)(Xh + (size_t)c0 * 128 + d0);
    bf16x8 u1 = *(const bf16x8*)(Xh + (size_t)c1 * 128 + d0);
#pragma unroll
    for (int k = 0; k < 8; ++k) s[k] += bf2f((ushort)u0[k]) + bf2f((ushort)u1[k]);
  }
  if (e < end) {
    int c = col[e];
    bf16x8 u = *(const bf16x8*)(Xh + (size_t)c * 128 + d0);
#pragma unroll
    for (int k = 0; k < 8; ++k) s[k] += bf2f((ushort)u[k]);
  }
  // combine the 4 edge groups (all lanes participate)
#pragma unroll
  for (int k = 0; k < 8; ++k) {
    s[k] += __shfl_xor(s[k], 16, 64);
    s[k] += __shfl_xor(s[k], 32, 64);
  }
  if (eg == 0) {
    int d = end - beg;
    float inv = 1.0f / (float)(d > 1 ? d : 1);
    bf16x8 o;
#pragma unroll
    for (int k = 0; k < 8; ++k) o[k] = (short)f2bf(s[k] * inv);
    *(bf16x8*)(Mh + (size_t)node * 128 + d0) = o;
  }
}

// ================= LDS-staged split-W MFMA GEMM =================
// H = relu(M @ Wl^T + X @ Wr^T + b); A bf16 (LDS-staged, XOR-swizzled);
// W split hi/lo swizzled fragment-native (L2-resident); 2 MFMA/product.
// Block: 4 waves = 64 rows x 128 cols; epilogue via LDS for dense stores.

__global__ __launch_bounds__(256) void gemm_kernel(
    const ushort* __restrict__ Mh, const ushort* __restrict__ Xh,
    const ushort* __restrict__ Wp, const float* __restrict__ bias,
    ushort* __restrict__ Hh, float* __restrict__ Hf, int n, int out_f32) {
  __shared__ char smem[32768];
  ushort* sM = (ushort*)smem;  // [64][128] swizzled content
  ushort* sX = sM + 8192;      // [64][128]
  int t = threadIdx.x;
  int lane = t & 63;
  int li = lane & 15, lg = lane >> 4;
  int w = t >> 6;
  int m0g = blockIdx.x * 64;
  int mw = (w >> 1) * 32;  // wave row offset (block-local)
  int n0 = (w & 1) * 64;

  // ---- stage M,X tiles: linear LDS dest + inverse-swizzled global source ----
  {
    int rowb = t >> 4, g = t & 15;
#pragma unroll
    for (int it = 0; it < 4; ++it) {
      int r = it * 16 + rowb;
      int srcrow = m0g + r;
      if (srcrow > n - 1) srcrow = n - 1;
      int sb = (g * 16) ^ ((r & 7) << 4);
      const char* gm = (const char*)Mh + (size_t)srcrow * 256 + sb;
      const char* gx = (const char*)Xh + (size_t)srcrow * 256 + sb;
      __builtin_amdgcn_global_load_lds(
          (const __attribute__((address_space(1))) void*)gm,
          (__attribute__((address_space(3))) void*)(sM + r * 128 + g * 8), 16, 0, 0);
      __builtin_amdgcn_global_load_lds(
          (const __attribute__((address_space(1))) void*)gx,
          (__attribute__((address_space(3))) void*)(sX + r * 128 + g * 8), 16, 0, 0);
    }
  }
  __syncthreads();

  f32x4 acc[2][4] = {};

#pragma unroll
  for (int ph = 0; ph < 2; ++ph) {
    const ushort* sA = ph ? sX : sM;
    const ushort* Wb = Wp + ph * 32768;
#pragma unroll
    for (int s = 0; s < 4; ++s) {
      int kg = s * 4 + lg;
      bf16x8 bh[4], bl[4];
#pragma unroll
      for (int nf = 0; nf < 4; ++nf) {
        const ushort* bp = Wb + (((n0 >> 4) + nf) << 11) + (kg * 16 + li) * 8;
        bh[nf] = *(const bf16x8*)bp;
        bl[nf] = *(const bf16x8*)(bp + 16384);
      }
      bf16x8 a[2];
#pragma unroll
      for (int mf = 0; mf < 2; ++mf) {
        int r = mw + mf * 16 + li;
        int kb = (kg * 16) ^ ((r & 7) << 4);  // swizzled read
        a[mf] = *(const bf16x8*)(sA + r * 128 + (kb >> 1));
      }
#pragma unroll
      for (int mf = 0; mf < 2; ++mf)
#pragma unroll
        for (int nf = 0; nf < 4; ++nf) {
          acc[mf][nf] =
              __builtin_amdgcn_mfma_f32_16x16x32_bf16(a[mf], bh[nf], acc[mf][nf], 0, 0, 0);
          acc[mf][nf] =
              __builtin_amdgcn_mfma_f32_16x16x32_bf16(a[mf], bl[nf], acc[mf][nf], 0, 0, 0);
        }
    }
  }

  __syncthreads();  // A-tile reads done; reuse smem for output staging

  if (!out_f32) {
    ushort* sO = (ushort*)smem;  // [64][128]
#pragma unroll
    for (int nf = 0; nf < 4; ++nf) {
      int c = n0 + nf * 16 + li;
      float bj = bias[c];
#pragma unroll
      for (int mf = 0; mf < 2; ++mf)
#pragma unroll
        for (int r = 0; r < 4; ++r) {
          int rl = mw + mf * 16 + lg * 4 + r;
          sO[rl * 128 + c] = f2bf(fmaxf(acc[mf][nf][r] + bj, 0.f));
        }
    }
    __syncthreads();
    int rowb = t >> 4, g = t & 15;
#pragma unroll
    for (int it = 0; it < 4; ++it) {
      int r = it * 16 + rowb;
      if (m0g + r < n)
        *(uint4*)(Hh + (size_t)(m0g + r) * 128 + g * 8) = *(const uint4*)(sO + r * 128 + g * 8);
    }
  } else {
    float* sF = (float*)smem;  // [64][128] fp32 = 32KB
#pragma unroll
    for (int nf = 0; nf < 4; ++nf) {
      int c = n0 + nf * 16 + li;
      float bj = bias[c];
#pragma unroll
      for (int mf = 0; mf < 2; ++mf)
#pragma unroll
        for (int r = 0; r < 4; ++r) {
          int rl = mw + mf * 16 + lg * 4 + r;
          sF[rl * 128 + c] = fmaxf(acc[mf][nf][r] + bj, 0.f);
        }
    }
    __syncthreads();
    int rowb = t >> 5, g = t & 31;
#pragma unroll
    for (int it = 0; it < 8; ++it) {
      int r = it * 8 + rowb;
      if (m0g + r < n)
        *(float4*)(Hf + (size_t)(m0g + r) * 128 + g * 4) = *(const float4*)(sF + r * 128 + g * 4);
    }
  }
}

// ================= global mean pool (boundary-based, no atomics) =================

__global__ void gbound_kernel(const int* __restrict__ batch, int* __restrict__ gstart, int n,
                              int G) {
  int i = blockIdx.x * 256 + threadIdx.x;
  if (i >= n) return;
  int b = batch[i];
  if (i == 0) {
    for (int g = 0; g <= b; ++g) gstart[g] = 0;
  } else {
    int p = batch[i - 1];
    for (int g = p + 1; g <= b; ++g) gstart[g] = i;
  }
  if (i == n - 1) {
    for (int g = b + 1; g <= G; ++g) gstart[g] = n;
  }
}

__global__ __launch_bounds__(256) void pool2_kernel(const float* __restrict__ H,
                                                    const int* __restrict__ gstart,
                                                    float* __restrict__ out) {
  int g = blockIdx.x;
  int t = threadIdx.x;
  int d4 = t & 31;
  int ro = t >> 5;
  int beg = gstart[g], end = gstart[g + 1];
  float4 acc = make_float4(0.f, 0.f, 0.f, 0.f);
#pragma unroll 4
  for (int r = beg + ro; r < end; r += 8) {
    float4 v = *(const float4*)(H + (size_t)r * 128 + d4 * 4);
    acc.x += v.x;
    acc.y += v.y;
    acc.z += v.z;
    acc.w += v.w;
  }
  __shared__ float4 sred[8][32];
  sred[ro][d4] = acc;
  __syncthreads();
  if (ro == 0) {
    float4 s = sred[0][d4];
#pragma unroll
    for (int r = 1; r < 8; ++r) {
      float4 v = sred[r][d4];
      s.x += v.x;
      s.y += v.y;
      s.z += v.z;
      s.w += v.w;
    }
    int cnt = end - beg;
    float inv = 1.0f / (float)(cnt > 1 ? cnt : 1);
    s.x *= inv;
    s.y *= inv;
    s.z *= inv;
    s.w *= inv;
    *(float4*)(out + (size_t)g * 128 + d4 * 4) = s;
  }
}

// ================= host =================

extern "C" void kernel_launch(void* const* d_in, const int* in_sizes, int n_in,
                              void* d_out, int out_size, void* d_ws, size_t ws_size,
                              hipStream_t stream) {
  const float* x = (const float*)d_in[0];
  const int* ei = (const int*)d_in[1];
  const int* batch = (const int*)d_in[2];
  const float* Wl0 = (const float*)d_in[3];
  const float* Wr0 = (const float*)d_in[4];
  const float* b0 = (const float*)d_in[5];
  const float* Wl1 = (const float*)d_in[6];
  const float* Wr1 = (const float*)d_in[7];
  const float* b1 = (const float*)d_in[8];
  const float* Wl2 = (const float*)d_in[9];
  const float* Wr2 = (const float*)d_in[10];
  const float* b2 = (const float*)d_in[11];
  float* out = (float*)d_out;

  const int N = in_sizes[0] / 128;
  const int E = in_sizes[1] / 2;
  const int G = out_size / 128;
  const int K = (N + 255) >> 8;
  const size_t NF = (size_t)N * 128;

  char* ws = (char*)d_ws;
  size_t off = 0;
  auto carve = [&](size_t bytes) {
    size_t o = align_up(off, 512);
    off = o + bytes;
    return (void*)(ws + o);
  };
  int* row_ptr = (int*)carve(((size_t)N + 1) * 4);
  int* bcnt = (int*)carve(1024 * 4);
  int* bbase = (int*)carve(1024 * 4);
  int* bcur = (int*)carve(1024 * 4);
  int* gstart = (int*)carve(((size_t)G + 1) * 4);
  int* col = (int*)carve((size_t)E * 4);
  ushort* P0 = (ushort*)carve(NF * 2);  // bf16 feature planes
  ushort* P1 = (ushort*)carve(NF * 2);
  ushort* M = (ushort*)carve(NF * 2);
  float* Hf = (float*)carve(NF * 4);  // final fp32 features
  ushort* Wp = (ushort*)carve(3 * 65536 * 2);
  (void)ws_size;

  int2* ebuf = (int2*)Hf;  // ebuf (12.8MB) aliases Hf (51.2MB); dead before layer2 gemm

  // ---- bucketed CSR build ----
  hipMemsetAsync(bcnt, 0, 1024 * 4, stream);
  int cgrid_e = (E + 4095) / 4096;
  hipLaunchKernelGGL(bhist_kernel, dim3(cgrid_e), dim3(256), 0, stream, ei, bcnt, E, K);
  hipLaunchKernelGGL(bscan_kernel, dim3(1), dim3(1024), 0, stream, bcnt, bbase, bcur, K);
  hipLaunchKernelGGL(bscatter_kernel, dim3(cgrid_e), dim3(256), 0, stream, ei, bcur, ebuf, E);
  hipLaunchKernelGGL(fine_kernel, dim3(K), dim3(256), 0, stream, bbase, ebuf, row_ptr, col, E, N,
                     K);

  // ---- conversions + graph bounds ----
  int cgrid = (int)((NF / 4 + 255) / 256);
  hipLaunchKernelGGL(convx_kernel, dim3(cgrid), dim3(256), 0, stream, x, P0, (int)(NF / 4));
  hipLaunchKernelGGL(wconv_kernel, dim3(16, 6), dim3(256), 0, stream, Wl0, Wr0, Wl1, Wr1, Wl2,
                     Wr2, Wp);
  int ngrid = (N + 255) / 256;
  hipLaunchKernelGGL(gbound_kernel, dim3(ngrid), dim3(256), 0, stream, batch, gstart, N, G);

  int agrid = (N + 3) / 4;
  int ggrid = (N + 63) / 64;

  // ---- layer 0 ----
  hipLaunchKernelGGL(aggr_kernel, dim3(agrid), dim3(256), 0, stream, P0, row_ptr, col, M, N);
  hipLaunchKernelGGL(gemm_kernel, dim3(ggrid), dim3(256), 0, stream, M, P0, Wp, b0, P1,
                     (float*)nullptr, N, 0);
  // ---- layer 1 ----
  hipLaunchKernelGGL(aggr_kernel, dim3(agrid), dim3(256), 0, stream, P1, row_ptr, col, M, N);
  hipLaunchKernelGGL(gemm_kernel, dim3(ggrid), dim3(256), 0, stream, M, P1, Wp + 65536, b1, P0,
                     (float*)nullptr, N, 0);
  // ---- layer 2 -> fp32 Hf ----
  hipLaunchKernelGGL(aggr_kernel, dim3(agrid), dim3(256), 0, stream, P0, row_ptr, col, M, N);
  hipLaunchKernelGGL(gemm_kernel, dim3(ggrid), dim3(256), 0, stream, M, P0, Wp + 2 * 65536, b2,
                     (ushort*)nullptr, Hf, N, 1);

  // ---- pool ----
  hipLaunchKernelGGL(pool2_kernel, dim3(G), dim3(256), 0, stream, Hf, gstart, out);
}